// Round 11
// baseline (434.355 us; speedup 1.0000x reference)
//
#include <hip/hip_runtime.h>

// f32 I/O. K=8 expert AEs, B=8192, D=1024, H=256.
//   h = relu(x @ W1[k] + b1[k]); recon = h @ W2[k] + b2[k]
//   err[k,b] = mean((recon-x)^2); out[b] = recon[argmin_k err, b]
// CHAMPION = R15 (verified 407.4us): R10 pass1 (2-stage reg dbuf phase A,
// h-in-regs phase B, [r_hi|k|r_lo] decode) + h-store + pass2_fast.
// Dead ends: R8 ring (spill), R9 per-ks LDS (LDS-pipe), R11 cap (spill),
// R12 deeper pipe (-8%), R7/R13 global_load_lds (crash x2), R14 setprio (-7%).
// pass1 is latency-pinned at 2 waves/SIMD; non-pass1 is now the target.
// R16 (this rev): pass1 ALREADY computes split-accurate recon for eacc ->
// store it (f32, 256MB, ws-guarded) and collapse pass2 to a row GATHER:
//   out[b] = recon[assign[b]][b]  (64MB traffic, ~12us)
// pass2_fast(+hglob) kept as fallback when ws < ~307MB; old pass2 as last
// resort. Output precision strictly improves (split recon vs bf16-hi).
// Tripwires: pass1 WRITE_SIZE ~256MB is EXPECTED (recon store, not spill);
// pass1 > 280us -> stores not hidden -> revert to R15.

#define KE 8
#define NB 8192
#define ND 1024
#define NH 256

typedef float f32x4 __attribute__((ext_vector_type(4)));
typedef short s16x8 __attribute__((ext_vector_type(8)));
typedef unsigned short u16x8 __attribute__((ext_vector_type(8)));

__device__ __forceinline__ float bf2f(unsigned short h) {
  union { unsigned int u; float f; } v; v.u = ((unsigned int)h) << 16; return v.f;
}
__device__ __forceinline__ unsigned short f2bf(float f) {
  union { unsigned int u; float f; } v; v.f = f;
  unsigned int u = v.u;
  u += 0x7fffu + ((u >> 16) & 1u);   // RTNE
  return (unsigned short)(u >> 16);
}
__device__ __forceinline__ void split2(float x, unsigned short& hi, unsigned short& lo) {
  hi = f2bf(x);
  lo = f2bf(x - bf2f(hi));
}

// ---- fused pack: W1, W2, x -> frag-ordered hi/lo arrays; also zeroes cnt.
__global__ __launch_bounds__(256) void pack_all(
    const float* __restrict__ W1, unsigned short* __restrict__ w1oh, unsigned short* __restrict__ w1ol,
    const float* __restrict__ W2, unsigned short* __restrict__ w2oh, unsigned short* __restrict__ w2ol,
    const float* __restrict__ xin, unsigned short* __restrict__ xoh, unsigned short* __restrict__ xol,
    unsigned int* __restrict__ cnt) {
  const int bx = blockIdx.x;
  const int tid = threadIdx.x;
  if (bx == 0 && tid < KE) cnt[tid] = 0;

  if (bx < 1024) {                           // ---- pack W1
    int gid = bx * 256 + tid;
    int L = gid & 63;
    int g = gid >> 6;
    int ks = g & 31;
    int ct = (g >> 5) & 15;
    int k = g >> 9;
    int col = ct * 16 + (L & 15);
    int kd0 = ks * 32 + (L >> 4) * 8;
    unsigned short th[8], tl[8];
#pragma unroll
    for (int j = 0; j < 8; ++j) {
      float v = W1[((size_t)k * ND + kd0 + j) * NH + col];
      split2(v, th[j], tl[j]);
    }
    size_t o = ((size_t)g * 64 + L) * 8;
    *(u16x8*)&w1oh[o] = *(u16x8*)th;
    *(u16x8*)&w1ol[o] = *(u16x8*)tl;
  } else if (bx < 2048) {                    // ---- pack W2
    int gid = (bx - 1024) * 256 + tid;
    int L = gid & 63;
    int g = gid >> 6;
    int ks = g & 7;
    int dt = (g >> 3) & 63;
    int k = g >> 9;
    int d2 = dt * 16 + (L & 15);
    int h0 = ks * 32 + (L >> 4) * 8;
    unsigned short th[8], tl[8];
#pragma unroll
    for (int j = 0; j < 8; ++j) {
      float v = W2[((size_t)k * NH + h0 + j) * ND + d2];
      split2(v, th[j], tl[j]);
    }
    size_t o = ((size_t)g * 64 + L) * 8;
    *(u16x8*)&w2oh[o] = *(u16x8*)th;
    *(u16x8*)&w2ol[o] = *(u16x8*)tl;
  } else {                                   // ---- pack x
    int gid = (bx - 2048) * 256 + tid;
    int L = gid & 63;
    int g = gid >> 6;
    int ks = g & 31;
    int rt = g >> 5;
    int row = rt * 16 + (L & 15);
    int kd0 = ks * 32 + (L >> 4) * 8;
    float4 a = *(const float4*)&xin[(size_t)row * ND + kd0];
    float4 b = *(const float4*)&xin[(size_t)row * ND + kd0 + 4];
    unsigned short th[8], tl[8];
    split2(a.x, th[0], tl[0]); split2(a.y, th[1], tl[1]);
    split2(a.z, th[2], tl[2]); split2(a.w, th[3], tl[3]);
    split2(b.x, th[4], tl[4]); split2(b.y, th[5], tl[5]);
    split2(b.z, th[6], tl[6]); split2(b.w, th[7], tl[7]);
    size_t o = ((size_t)g * 64 + L) * 8;
    *(u16x8*)&xoh[o] = *(u16x8*)th;
    *(u16x8*)&xol[o] = *(u16x8*)tl;
  }
}

// load one phase-A stage (16 frags, 256B/lane) into named register buffers
#define LOAD_STAGE(ah, al, bh, bl, it)                  \
  do {                                                  \
    _Pragma("unroll")                                   \
    for (int q_ = 0; q_ < 4; ++q_) {                    \
      int o_ = xo[q_] + (it) * 512;                     \
      ah[q_] = *(const s16x8*)&xph[o_];                 \
      al[q_] = *(const s16x8*)&xpl[o_];                 \
    }                                                   \
    _Pragma("unroll")                                   \
    for (int q_ = 0; q_ < 4; ++q_) {                    \
      int o_ = wo1[q_] + (it) * 512;                    \
      bh[q_] = *(const s16x8*)&w1ph[o_];                \
      bl[q_] = *(const s16x8*)&w1pl[o_];                \
    }                                                   \
  } while (0)

// 48 MFMAs (3-product split) on one stage
#define MFMA_STAGE(ah, al, bh, bl)                                                                   \
  do {                                                                                               \
    _Pragma("unroll")                                                                                \
    for (int nt_ = 0; nt_ < 4; ++nt_)                                                                \
      _Pragma("unroll")                                                                              \
      for (int mt_ = 0; mt_ < 4; ++mt_) {                                                            \
        acc1[mt_][nt_] = __builtin_amdgcn_mfma_f32_16x16x32_bf16(ah[mt_], bh[nt_], acc1[mt_][nt_], 0, 0, 0); \
        acc1[mt_][nt_] = __builtin_amdgcn_mfma_f32_16x16x32_bf16(ah[mt_], bl[nt_], acc1[mt_][nt_], 0, 0, 0); \
        acc1[mt_][nt_] = __builtin_amdgcn_mfma_f32_16x16x32_bf16(al[mt_], bh[nt_], acc1[mt_][nt_], 0, 0, 0); \
      }                                                                                              \
  } while (0)

// ---- pass 1: split-precision err[K][B]. BM=64, grid 1024.
// Champion decode: bx bits [r_hi | k(3b) | r_lo(3b)] (R10, verified).
__global__ __launch_bounds__(256, 2) void ae_pass1(
    const unsigned short* __restrict__ xph, const unsigned short* __restrict__ xpl,
    const float* __restrict__ x,
    const unsigned short* __restrict__ w1ph, const unsigned short* __restrict__ w1pl,
    const float* __restrict__ b1,
    const unsigned short* __restrict__ w2ph, const unsigned short* __restrict__ w2pl,
    const float* __restrict__ b2, float* __restrict__ err,
    unsigned short* __restrict__ hglob, float* __restrict__ recon) {
  __shared__ union {
    struct { unsigned short h[64][256]; unsigned short l[64][256]; } hs;  // 65536 B
    float errp[4][64];
  } s;

  const int tid = threadIdx.x;
  const int wv = tid >> 6;
  const int lane = tid & 63;
  const int lo = lane & 15;
  const int quad = lane >> 4;
  const int k = (blockIdx.x >> 3) & 7;
  const int rtile = (int)(((blockIdx.x >> 6) << 3) | (blockIdx.x & 7));
  const int r0 = rtile * 64;

  // ---------- phase A: h = relu(x@W1+b1). Barrier-free, register-pipelined.
  int xo[4], wo1[4];
#pragma unroll
  for (int mt = 0; mt < 4; ++mt) xo[mt] = ((rtile * 4 + mt) * 32) * 512 + lane * 8;
#pragma unroll
  for (int nt = 0; nt < 4; ++nt) wo1[nt] = ((k * 16 + wv * 4 + nt) * 32) * 512 + lane * 8;

  f32x4 acc1[4][4];
#pragma unroll
  for (int mt = 0; mt < 4; ++mt)
#pragma unroll
    for (int nt = 0; nt < 4; ++nt) acc1[mt][nt] = (f32x4){0.f, 0.f, 0.f, 0.f};

  s16x8 Aah[4], Aal[4], Abh[4], Abl[4];
  s16x8 Bah[4], Bal[4], Bbh[4], Bbl[4];
  LOAD_STAGE(Aah, Aal, Abh, Abl, 0);
  LOAD_STAGE(Bah, Bal, Bbh, Bbl, 1);
  for (int it = 0; it < 32; it += 2) {
    MFMA_STAGE(Aah, Aal, Abh, Abl);
    if (it + 2 < 32) LOAD_STAGE(Aah, Aal, Abh, Abl, it + 2);
    MFMA_STAGE(Bah, Bal, Bbh, Bbl);
    if (it + 3 < 32) LOAD_STAGE(Bah, Bal, Bbh, Bbl, it + 3);
  }

  // epilogue A: +b1, relu, split h -> LDS swizzled; optional h store (fallback
  // path only; disabled when recon path active).
  const bool wh = (hglob != nullptr);
#pragma unroll
  for (int nt = 0; nt < 4; ++nt) {
    float b1v = b1[(size_t)k * NH + wv * 64 + nt * 16 + lo];
#pragma unroll
    for (int mt = 0; mt < 4; ++mt)
#pragma unroll
      for (int i = 0; i < 4; ++i) {
        float v = acc1[mt][nt][i] + b1v;
        v = v > 0.f ? v : 0.f;
        unsigned short vh, vl;
        split2(v, vh, vl);
        int row = mt * 16 + quad * 4 + i, col = wv * 64 + nt * 16 + lo;
        int sc = col ^ ((row & 7) << 3);
        s.hs.h[row][sc] = vh;
        s.hs.l[row][sc] = vl;
        if (wh) hglob[((size_t)k * NB + r0 + row) * NH + col] = vh;
      }
  }
  __syncthreads();   // the ONE inter-phase barrier

  // ---------- phase B: recon = h@W2+b2. Wave wv owns d2-strip [wv*256, +256).
  // h A-frags dt-invariant: hold a 2-row-tile chunk in registers (128 VGPR)
  // and stream W2 frags (disjoint per wave). Optionally store split-accurate
  // recon (f32) for the gather-based output path.
  const bool wrc = (recon != nullptr);
  float eacc[4][4];
#pragma unroll
  for (int mt = 0; mt < 4; ++mt)
#pragma unroll
    for (int i = 0; i < 4; ++i) eacc[mt][i] = 0.f;

  const int w2base = ((k * 64 + wv * 16) * 8) * 512 + lane * 8;

  for (int mc = 0; mc < 2; ++mc) {
    s16x8 hh[2][8], hl[2][8];
#pragma unroll
    for (int m2 = 0; m2 < 2; ++m2) {
      int row = (mc * 2 + m2) * 16 + lo;
      int rbase = row * 256;
      int sw = (row & 7) << 3;
#pragma unroll
      for (int ks = 0; ks < 8; ++ks) {
        int off = rbase + ((ks * 32 + quad * 8) ^ sw);
        hh[m2][ks] = *(const s16x8*)(&s.hs.h[0][0] + off);
        hl[m2][ks] = *(const s16x8*)(&s.hs.l[0][0] + off);
      }
    }
    for (int dt = 0; dt < 16; ++dt) {
      f32x4 acc2[2];
      acc2[0] = (f32x4){0.f, 0.f, 0.f, 0.f};
      acc2[1] = (f32x4){0.f, 0.f, 0.f, 0.f};
#pragma unroll
      for (int ks = 0; ks < 8; ++ks) {
        int wo = w2base + dt * 4096 + ks * 512;
        s16x8 bh = *(const s16x8*)&w2ph[wo];
        s16x8 bl = *(const s16x8*)&w2pl[wo];
#pragma unroll
        for (int m2 = 0; m2 < 2; ++m2) {
          acc2[m2] = __builtin_amdgcn_mfma_f32_16x16x32_bf16(hh[m2][ks], bh, acc2[m2], 0, 0, 0);
          acc2[m2] = __builtin_amdgcn_mfma_f32_16x16x32_bf16(hh[m2][ks], bl, acc2[m2], 0, 0, 0);
          acc2[m2] = __builtin_amdgcn_mfma_f32_16x16x32_bf16(hl[m2][ks], bh, acc2[m2], 0, 0, 0);
        }
      }
      const int d2 = wv * 256 + dt * 16 + lo;
      float b2v = b2[(size_t)k * ND + d2];
#pragma unroll
      for (int m2 = 0; m2 < 2; ++m2)
#pragma unroll
        for (int i = 0; i < 4; ++i) {
          int row = (mc * 2 + m2) * 16 + quad * 4 + i;
          float rec = acc2[m2][i] + b2v;
          if (wrc) recon[((size_t)k * NB + r0 + row) * ND + d2] = rec;
          float xv = x[(size_t)(r0 + row) * ND + d2];
          float dd = rec - xv;
          eacc[mc * 2 + m2][i] += dd * dd;
        }
    }
  }

  __syncthreads();   // all hs reads done before errp aliases the union
#pragma unroll
  for (int mt = 0; mt < 4; ++mt)
#pragma unroll
    for (int i = 0; i < 4; ++i) {
      float v = eacc[mt][i];
      v += __shfl_xor(v, 1, 16);
      v += __shfl_xor(v, 2, 16);
      v += __shfl_xor(v, 4, 16);
      v += __shfl_xor(v, 8, 16);
      if (lo == 0) s.errp[wv][mt * 16 + quad * 4 + i] = v;
    }
  __syncthreads();
  if (tid < 64)
    err[(size_t)k * NB + r0 + tid] =
        (s.errp[0][tid] + s.errp[1][tid] + s.errp[2][tid] + s.errp[3][tid]) * (1.0f / (float)ND);
}

// ---- argmin: winner expert per row (+ bucket for fallback paths)
__global__ __launch_bounds__(256) void ae_argmin(const float* __restrict__ err,
                                                 unsigned int* __restrict__ cnt,
                                                 int* __restrict__ bucket,
                                                 int* __restrict__ assign) {
  __shared__ unsigned int lc[KE];
  __shared__ unsigned int base[KE];
  int tid = threadIdx.x;
  if (tid < KE) lc[tid] = 0;
  __syncthreads();
  int b = blockIdx.x * 256 + tid;
  float best = err[b];
  int kmin = 0;
#pragma unroll
  for (int j = 1; j < KE; ++j) {
    float e = err[(size_t)j * NB + b];
    if (e < best) { best = e; kmin = j; }   // strict < == first-min (jnp.argmin)
  }
  assign[b] = kmin;
  unsigned int lpos = atomicAdd(&lc[kmin], 1u);
  __syncthreads();
  if (tid < KE) base[tid] = atomicAdd(&cnt[tid], lc[tid]);
  __syncthreads();
  bucket[(size_t)kmin * NB + (int)(base[kmin] + lpos)] = b;
}

// ---- gather: out[b] = recon[assign[b]][b]. One block per row, float4 copies.
__global__ __launch_bounds__(256) void ae_gather(const float* __restrict__ recon,
                                                 const int* __restrict__ assign,
                                                 float* __restrict__ out) {
  const int b = blockIdx.x;
  const int kmin = assign[b];
  const float4* src = (const float4*)&recon[((size_t)kmin * NB + b) * ND];
  float4* dst = (float4*)&out[(size_t)b * ND];
  dst[threadIdx.x] = src[threadIdx.x];   // 256 x 16B = 4KB row
}

// ---- pass 2 FAST (fallback 1): h precomputed -> phase B only.
__global__ __launch_bounds__(256) void ae_pass2_fast(
    const unsigned short* __restrict__ hglob,
    const unsigned short* __restrict__ w2ph, const float* __restrict__ b2,
    const unsigned int* __restrict__ cnt, const int* __restrict__ bucket,
    float* __restrict__ out) {
  __shared__ int rid[64];

  const int k = blockIdx.x & 7;
  const int cv = (int)cnt[k];
  const int t0 = (blockIdx.x >> 3) * 64;
  if (t0 >= cv) return;                     // uniform exit before any barrier
  const int nrows = min(64, cv - t0);

  const int tid = threadIdx.x;
  const int wv = tid >> 6;
  const int lane = tid & 63;
  const int lo = lane & 15;
  const int quad = lane >> 4;

  if (tid < 64) {
    int idx = t0 + tid;
    rid[tid] = bucket[(size_t)k * NB + (idx < cv ? idx : t0)];
  }
  __syncthreads();

  const int grow = rid[wv * 16 + lo];       // this lane's winner row
  s16x8 af[8];                              // its 8 A-frag slices (32 VGPR)
  const size_t hbase = ((size_t)k * NB + grow) * NH + quad * 8;
#pragma unroll
  for (int ks = 0; ks < 8; ++ks)
    af[ks] = *(const s16x8*)&hglob[hbase + ks * 32];

  for (int c = 0; c < 32; ++c) {
    f32x4 acc2[2];
    acc2[0] = (f32x4){0.f, 0.f, 0.f, 0.f};
    acc2[1] = (f32x4){0.f, 0.f, 0.f, 0.f};
#pragma unroll
    for (int ks = 0; ks < 8; ++ks) {
#pragma unroll
      for (int nt = 0; nt < 2; ++nt) {
        s16x8 bfr = *(const s16x8*)&w2ph[(((size_t)(k * 64 + c * 2 + nt) * 8) + ks) * 512 + lane * 8];
        acc2[nt] = __builtin_amdgcn_mfma_f32_16x16x32_bf16(af[ks], bfr, acc2[nt], 0, 0, 0);
      }
    }
#pragma unroll
    for (int nt = 0; nt < 2; ++nt) {
      float b2v = b2[(size_t)k * ND + c * 32 + nt * 16 + lo];
#pragma unroll
      for (int i = 0; i < 4; ++i) {
        int row = wv * 16 + quad * 4 + i;
        if (row < nrows)
          out[(size_t)rid[row] * ND + c * 32 + nt * 16 + lo] = acc2[nt][i] + b2v;
      }
    }
  }
}

// ---- pass 2 (fallback 2, ws tiny): recompute winner rows from x
__global__ __launch_bounds__(256) void ae_pass2(
    const float* __restrict__ x,
    const unsigned short* __restrict__ w1ph, const float* __restrict__ b1,
    const unsigned short* __restrict__ w2ph, const float* __restrict__ b2,
    const unsigned int* __restrict__ cnt, const int* __restrict__ bucket,
    float* __restrict__ out) {
  __shared__ unsigned short hs[64][NH + 8];   // 33792 B
  __shared__ unsigned short xs[64][40];       // 5120 B
  __shared__ int rid[64];

  const int k = blockIdx.x & 7;
  const int cv = (int)cnt[k];
  const int t0 = (blockIdx.x >> 3) * 64;
  if (t0 >= cv) return;                     // uniform exit before any barrier
  const int nrows = min(64, cv - t0);

  const int tid = threadIdx.x;
  const int wv = tid >> 6;
  const int lane = tid & 63;
  const int lo = lane & 15;
  const int quad = lane >> 4;
  const int srow = tid >> 2, scol = (tid & 3) * 8;

  if (tid < 64) {
    int idx = t0 + tid;
    rid[tid] = bucket[(size_t)k * NB + (idx < cv ? idx : t0)];
  }
  __syncthreads();
  const int grow = rid[srow];

  f32x4 acc1[4][4];
#pragma unroll
  for (int mt = 0; mt < 4; ++mt)
#pragma unroll
    for (int nt = 0; nt < 4; ++nt) acc1[mt][nt] = (f32x4){0.f, 0.f, 0.f, 0.f};

  for (int it = 0; it < 32; ++it) {
    float4 xa = *(const float4*)&x[(size_t)grow * ND + it * 32 + scol];
    float4 xb = *(const float4*)&x[(size_t)grow * ND + it * 32 + scol + 4];
    s16x8 bfr[4];
#pragma unroll
    for (int nt = 0; nt < 4; ++nt)
      bfr[nt] = *(const s16x8*)&w1ph[(((size_t)(k * 16 + wv * 4 + nt) * 32) + it) * 512 + lane * 8];
    __syncthreads();   // prev frag reads done
    unsigned short t[8];
    t[0] = f2bf(xa.x); t[1] = f2bf(xa.y); t[2] = f2bf(xa.z); t[3] = f2bf(xa.w);
    t[4] = f2bf(xb.x); t[5] = f2bf(xb.y); t[6] = f2bf(xb.z); t[7] = f2bf(xb.w);
    *(u16x8*)&xs[srow][scol] = *(u16x8*)t;
    __syncthreads();
    s16x8 af[4];
#pragma unroll
    for (int mt = 0; mt < 4; ++mt) af[mt] = *(const s16x8*)&xs[mt * 16 + lo][quad * 8];
#pragma unroll
    for (int mt = 0; mt < 4; ++mt)
#pragma unroll
      for (int nt = 0; nt < 4; ++nt)
        acc1[mt][nt] = __builtin_amdgcn_mfma_f32_16x16x32_bf16(af[mt], bfr[nt], acc1[mt][nt], 0, 0, 0);
  }
  __syncthreads();

#pragma unroll
  for (int nt = 0; nt < 4; ++nt) {
    float b1v = b1[(size_t)k * NH + wv * 64 + nt * 16 + lo];
#pragma unroll
    for (int mt = 0; mt < 4; ++mt)
#pragma unroll
      for (int i = 0; i < 4; ++i) {
        float v = acc1[mt][nt][i] + b1v;
        v = v > 0.f ? v : 0.f;
        hs[mt * 16 + quad * 4 + i][wv * 64 + nt * 16 + lo] = f2bf(v);
      }
  }
  __syncthreads();

  // phase B: wave wv owns rows [wv*16, +16); d2 chunks of 32; no barriers.
  for (int c = 0; c < 32; ++c) {
    f32x4 acc2[2];
    acc2[0] = (f32x4){0.f, 0.f, 0.f, 0.f};
    acc2[1] = (f32x4){0.f, 0.f, 0.f, 0.f};
#pragma unroll
    for (int ks = 0; ks < 8; ++ks) {
      s16x8 af = *(const s16x8*)&hs[wv * 16 + lo][ks * 32 + quad * 8];
#pragma unroll
      for (int nt = 0; nt < 2; ++nt) {
        s16x8 bfr = *(const s16x8*)&w2ph[(((size_t)(k * 64 + c * 2 + nt) * 8) + ks) * 512 + lane * 8];
        acc2[nt] = __builtin_amdgcn_mfma_f32_16x16x32_bf16(af, bfr, acc2[nt], 0, 0, 0);
      }
    }
#pragma unroll
    for (int nt = 0; nt < 2; ++nt) {
      float b2v = b2[(size_t)k * ND + c * 32 + nt * 16 + lo];
#pragma unroll
      for (int i = 0; i < 4; ++i) {
        int row = wv * 16 + quad * 4 + i;
        if (row < nrows)
          out[(size_t)rid[row] * ND + c * 32 + nt * 16 + lo] = acc2[nt][i] + b2v;
      }
    }
  }
}

extern "C" void kernel_launch(void* const* d_in, const int* in_sizes, int n_in,
                              void* d_out, int out_size, void* d_ws, size_t ws_size,
                              hipStream_t stream) {
  (void)in_sizes; (void)n_in; (void)out_size;
  const float* x  = (const float*)d_in[0];
  const float* W1 = (const float*)d_in[1];
  const float* b1 = (const float*)d_in[2];
  const float* W2 = (const float*)d_in[3];
  const float* b2 = (const float*)d_in[4];
  float* out = (float*)d_out;

  char* ws = (char*)d_ws;
  const size_t szW = (size_t)KE * ND * NH * sizeof(unsigned short);  // 4 MB
  const size_t szX = (size_t)NB * ND * sizeof(unsigned short);       // 16.78 MB
  unsigned short* w1ph = (unsigned short*)(ws);
  unsigned short* w1pl = (unsigned short*)(ws + szW);
  unsigned short* w2ph = (unsigned short*)(ws + 2 * szW);
  unsigned short* w2pl = (unsigned short*)(ws + 3 * szW);
  unsigned short* xph  = (unsigned short*)(ws + 4 * szW);
  unsigned short* xpl  = (unsigned short*)(ws + 4 * szW + szX);
  char* tail           = ws + 4 * szW + 2 * szX;
  float* err           = (float*)tail;
  int* bucket          = (int*)(tail + (size_t)KE * NB * sizeof(float));
  unsigned int* cnt    = (unsigned int*)(tail + (size_t)KE * NB * sizeof(float)
                                         + (size_t)KE * NB * sizeof(int));
  int* assign          = (int*)(tail + (size_t)KE * NB * sizeof(float)
                                + (size_t)KE * NB * sizeof(int) + 4096);
  // base ~50.4 MB; then (tiered by ws_size): recon f32 256MB, or hglob 32MB.
  size_t base = 4 * szW + 2 * szX + (size_t)KE * NB * (sizeof(float) + sizeof(int))
                + 4096 + (size_t)NB * sizeof(int) + 4096;
  size_t rbytes = (size_t)KE * NB * ND * sizeof(float);              // 256 MB
  size_t hbytes = (size_t)KE * NB * NH * sizeof(unsigned short);     // 32 MB
  float* recon = (ws_size >= base + rbytes) ? (float*)(ws + base) : nullptr;
  unsigned short* hglob = (!recon && ws_size >= base + hbytes)
                              ? (unsigned short*)(ws + base) : nullptr;

  pack_all<<<6144, 256, 0, stream>>>(W1, w1ph, w1pl, W2, w2ph, w2pl, x, xph, xpl, cnt);
  ae_pass1<<<1024, 256, 0, stream>>>(xph, xpl, x, w1ph, w1pl, b1, w2ph, w2pl, b2, err,
                                     hglob, recon);
  ae_argmin<<<NB / 256, 256, 0, stream>>>(err, cnt, bucket, assign);
  if (recon)
    ae_gather<<<NB, 256, 0, stream>>>(recon, assign, out);
  else if (hglob)
    ae_pass2_fast<<<1024, 256, 0, stream>>>(hglob, w2ph, b2, cnt, bucket, out);
  else
    ae_pass2<<<1024, 256, 0, stream>>>(x, w1ph, b1, w2ph, b2, cnt, bucket, out);
}

// Round 12
// 372.005 us; speedup vs baseline: 1.1676x; 1.1676x over previous
//
#include <hip/hip_runtime.h>

// f32 I/O. K=8 expert AEs, B=8192, D=1024, H=256.
//   h = relu(x @ W1[k] + b1[k]); recon = h @ W2[k] + b2[k]
//   err[k,b] = mean((recon-x)^2); out[b] = recon[argmin_k err, b]
// CHAMPION = R15 (verified 407.4us): pass1 (2-stage reg dbuf phase A,
// h-in-regs phase B, [r_hi|k|r_lo] decode) + h-store + pass2_fast.
// Dead ends: R8 ring (spill), R9 per-ks LDS (LDS-pipe), R11 cap (spill),
// R12 deeper pipe (-8%), R7/R13 global_load_lds (crash x2), R14 setprio
// (-7%), R16 runtime-branch recon store (dead `if(wrc)` in hot loop cost
// 25us; recon f32 tier never activated -> ws_size < ~307MB).
// R17 (this rev): templated ae_pass1_t<MODE> (compile-time, no hot branches):
//   MODE 1 = EXACT R15 pass1 (hglob store)        [fallback, proven 232us]
//   MODE 2 = phase-B stores f2bf(rec) -> reconb bf16 (128MB; fits smaller ws
//            than f32's 256MB). Output = split recon + one bf16 rounding
//            (MORE accurate than pass2_fast's recompute). pass2 -> gather.
// Tiered launch on ws_size: reconb(>=~185MB) > hglob(>=~83MB) > plain pass2.
// Tripwires: MODE2 pass1 WRITE ~130MB expected (not spill). If ws too small,
// counters = R15 exactly and the plateau is confirmed.

#define KE 8
#define NB 8192
#define ND 1024
#define NH 256

typedef float f32x4 __attribute__((ext_vector_type(4)));
typedef short s16x8 __attribute__((ext_vector_type(8)));
typedef unsigned short u16x8 __attribute__((ext_vector_type(8)));
typedef unsigned short u16x4 __attribute__((ext_vector_type(4)));

__device__ __forceinline__ float bf2f(unsigned short h) {
  union { unsigned int u; float f; } v; v.u = ((unsigned int)h) << 16; return v.f;
}
__device__ __forceinline__ unsigned short f2bf(float f) {
  union { unsigned int u; float f; } v; v.f = f;
  unsigned int u = v.u;
  u += 0x7fffu + ((u >> 16) & 1u);   // RTNE
  return (unsigned short)(u >> 16);
}
__device__ __forceinline__ void split2(float x, unsigned short& hi, unsigned short& lo) {
  hi = f2bf(x);
  lo = f2bf(x - bf2f(hi));
}

// ---- fused pack: W1, W2, x -> frag-ordered hi/lo arrays; also zeroes cnt.
__global__ __launch_bounds__(256) void pack_all(
    const float* __restrict__ W1, unsigned short* __restrict__ w1oh, unsigned short* __restrict__ w1ol,
    const float* __restrict__ W2, unsigned short* __restrict__ w2oh, unsigned short* __restrict__ w2ol,
    const float* __restrict__ xin, unsigned short* __restrict__ xoh, unsigned short* __restrict__ xol,
    unsigned int* __restrict__ cnt) {
  const int bx = blockIdx.x;
  const int tid = threadIdx.x;
  if (bx == 0 && tid < KE) cnt[tid] = 0;

  if (bx < 1024) {                           // ---- pack W1
    int gid = bx * 256 + tid;
    int L = gid & 63;
    int g = gid >> 6;
    int ks = g & 31;
    int ct = (g >> 5) & 15;
    int k = g >> 9;
    int col = ct * 16 + (L & 15);
    int kd0 = ks * 32 + (L >> 4) * 8;
    unsigned short th[8], tl[8];
#pragma unroll
    for (int j = 0; j < 8; ++j) {
      float v = W1[((size_t)k * ND + kd0 + j) * NH + col];
      split2(v, th[j], tl[j]);
    }
    size_t o = ((size_t)g * 64 + L) * 8;
    *(u16x8*)&w1oh[o] = *(u16x8*)th;
    *(u16x8*)&w1ol[o] = *(u16x8*)tl;
  } else if (bx < 2048) {                    // ---- pack W2
    int gid = (bx - 1024) * 256 + tid;
    int L = gid & 63;
    int g = gid >> 6;
    int ks = g & 7;
    int dt = (g >> 3) & 63;
    int k = g >> 9;
    int d2 = dt * 16 + (L & 15);
    int h0 = ks * 32 + (L >> 4) * 8;
    unsigned short th[8], tl[8];
#pragma unroll
    for (int j = 0; j < 8; ++j) {
      float v = W2[((size_t)k * NH + h0 + j) * ND + d2];
      split2(v, th[j], tl[j]);
    }
    size_t o = ((size_t)g * 64 + L) * 8;
    *(u16x8*)&w2oh[o] = *(u16x8*)th;
    *(u16x8*)&w2ol[o] = *(u16x8*)tl;
  } else {                                   // ---- pack x
    int gid = (bx - 2048) * 256 + tid;
    int L = gid & 63;
    int g = gid >> 6;
    int ks = g & 31;
    int rt = g >> 5;
    int row = rt * 16 + (L & 15);
    int kd0 = ks * 32 + (L >> 4) * 8;
    float4 a = *(const float4*)&xin[(size_t)row * ND + kd0];
    float4 b = *(const float4*)&xin[(size_t)row * ND + kd0 + 4];
    unsigned short th[8], tl[8];
    split2(a.x, th[0], tl[0]); split2(a.y, th[1], tl[1]);
    split2(a.z, th[2], tl[2]); split2(a.w, th[3], tl[3]);
    split2(b.x, th[4], tl[4]); split2(b.y, th[5], tl[5]);
    split2(b.z, th[6], tl[6]); split2(b.w, th[7], tl[7]);
    size_t o = ((size_t)g * 64 + L) * 8;
    *(u16x8*)&xoh[o] = *(u16x8*)th;
    *(u16x8*)&xol[o] = *(u16x8*)tl;
  }
}

// load one phase-A stage (16 frags, 256B/lane) into named register buffers
#define LOAD_STAGE(ah, al, bh, bl, it)                  \
  do {                                                  \
    _Pragma("unroll")                                   \
    for (int q_ = 0; q_ < 4; ++q_) {                    \
      int o_ = xo[q_] + (it) * 512;                     \
      ah[q_] = *(const s16x8*)&xph[o_];                 \
      al[q_] = *(const s16x8*)&xpl[o_];                 \
    }                                                   \
    _Pragma("unroll")                                   \
    for (int q_ = 0; q_ < 4; ++q_) {                    \
      int o_ = wo1[q_] + (it) * 512;                    \
      bh[q_] = *(const s16x8*)&w1ph[o_];                \
      bl[q_] = *(const s16x8*)&w1pl[o_];                \
    }                                                   \
  } while (0)

// 48 MFMAs (3-product split) on one stage
#define MFMA_STAGE(ah, al, bh, bl)                                                                   \
  do {                                                                                               \
    _Pragma("unroll")                                                                                \
    for (int nt_ = 0; nt_ < 4; ++nt_)                                                                \
      _Pragma("unroll")                                                                              \
      for (int mt_ = 0; mt_ < 4; ++mt_) {                                                            \
        acc1[mt_][nt_] = __builtin_amdgcn_mfma_f32_16x16x32_bf16(ah[mt_], bh[nt_], acc1[mt_][nt_], 0, 0, 0); \
        acc1[mt_][nt_] = __builtin_amdgcn_mfma_f32_16x16x32_bf16(ah[mt_], bl[nt_], acc1[mt_][nt_], 0, 0, 0); \
        acc1[mt_][nt_] = __builtin_amdgcn_mfma_f32_16x16x32_bf16(al[mt_], bh[nt_], acc1[mt_][nt_], 0, 0, 0); \
      }                                                                                              \
  } while (0)

// ---- pass 1: split-precision err[K][B]. BM=64, grid 1024.
// Champion decode: bx bits [r_hi | k(3b) | r_lo(3b)] (R10, verified).
// MODE (compile-time): 0 = no aux store; 1 = hglob store (R15); 2 = bf16
// recon store. No runtime branches in hot paths (R16 lesson).
template <int MODE>
__global__ __launch_bounds__(256, 2) void ae_pass1_t(
    const unsigned short* __restrict__ xph, const unsigned short* __restrict__ xpl,
    const float* __restrict__ x,
    const unsigned short* __restrict__ w1ph, const unsigned short* __restrict__ w1pl,
    const float* __restrict__ b1,
    const unsigned short* __restrict__ w2ph, const unsigned short* __restrict__ w2pl,
    const float* __restrict__ b2, float* __restrict__ err,
    unsigned short* __restrict__ hglob, unsigned short* __restrict__ reconb) {
  __shared__ union {
    struct { unsigned short h[64][256]; unsigned short l[64][256]; } hs;  // 65536 B
    float errp[4][64];
  } s;

  const int tid = threadIdx.x;
  const int wv = tid >> 6;
  const int lane = tid & 63;
  const int lo = lane & 15;
  const int quad = lane >> 4;
  const int k = (blockIdx.x >> 3) & 7;
  const int rtile = (int)(((blockIdx.x >> 6) << 3) | (blockIdx.x & 7));
  const int r0 = rtile * 64;

  // ---------- phase A: h = relu(x@W1+b1). Barrier-free, register-pipelined.
  int xo[4], wo1[4];
#pragma unroll
  for (int mt = 0; mt < 4; ++mt) xo[mt] = ((rtile * 4 + mt) * 32) * 512 + lane * 8;
#pragma unroll
  for (int nt = 0; nt < 4; ++nt) wo1[nt] = ((k * 16 + wv * 4 + nt) * 32) * 512 + lane * 8;

  f32x4 acc1[4][4];
#pragma unroll
  for (int mt = 0; mt < 4; ++mt)
#pragma unroll
    for (int nt = 0; nt < 4; ++nt) acc1[mt][nt] = (f32x4){0.f, 0.f, 0.f, 0.f};

  s16x8 Aah[4], Aal[4], Abh[4], Abl[4];
  s16x8 Bah[4], Bal[4], Bbh[4], Bbl[4];
  LOAD_STAGE(Aah, Aal, Abh, Abl, 0);
  LOAD_STAGE(Bah, Bal, Bbh, Bbl, 1);
  for (int it = 0; it < 32; it += 2) {
    MFMA_STAGE(Aah, Aal, Abh, Abl);
    if (it + 2 < 32) LOAD_STAGE(Aah, Aal, Abh, Abl, it + 2);
    MFMA_STAGE(Bah, Bal, Bbh, Bbl);
    if (it + 3 < 32) LOAD_STAGE(Bah, Bal, Bbh, Bbl, it + 3);
  }

  // epilogue A: +b1, relu, split h -> LDS swizzled; MODE1: also store h.
#pragma unroll
  for (int nt = 0; nt < 4; ++nt) {
    float b1v = b1[(size_t)k * NH + wv * 64 + nt * 16 + lo];
#pragma unroll
    for (int mt = 0; mt < 4; ++mt)
#pragma unroll
      for (int i = 0; i < 4; ++i) {
        float v = acc1[mt][nt][i] + b1v;
        v = v > 0.f ? v : 0.f;
        unsigned short vh, vl;
        split2(v, vh, vl);
        int row = mt * 16 + quad * 4 + i, col = wv * 64 + nt * 16 + lo;
        int sc = col ^ ((row & 7) << 3);
        s.hs.h[row][sc] = vh;
        s.hs.l[row][sc] = vl;
        if (MODE == 1) hglob[((size_t)k * NB + r0 + row) * NH + col] = vh;
      }
  }
  __syncthreads();   // the ONE inter-phase barrier

  // ---------- phase B: recon = h@W2+b2. Wave wv owns d2-strip [wv*256, +256).
  // h A-frags dt-invariant: 2-row-tile chunk in regs, W2 streamed.
  // MODE2: store split-accurate recon (bf16) for the gather output path.
  float eacc[4][4];
#pragma unroll
  for (int mt = 0; mt < 4; ++mt)
#pragma unroll
    for (int i = 0; i < 4; ++i) eacc[mt][i] = 0.f;

  const int w2base = ((k * 64 + wv * 16) * 8) * 512 + lane * 8;

  for (int mc = 0; mc < 2; ++mc) {
    s16x8 hh[2][8], hl[2][8];
#pragma unroll
    for (int m2 = 0; m2 < 2; ++m2) {
      int row = (mc * 2 + m2) * 16 + lo;
      int rbase = row * 256;
      int sw = (row & 7) << 3;
#pragma unroll
      for (int ks = 0; ks < 8; ++ks) {
        int off = rbase + ((ks * 32 + quad * 8) ^ sw);
        hh[m2][ks] = *(const s16x8*)(&s.hs.h[0][0] + off);
        hl[m2][ks] = *(const s16x8*)(&s.hs.l[0][0] + off);
      }
    }
    for (int dt = 0; dt < 16; ++dt) {
      f32x4 acc2[2];
      acc2[0] = (f32x4){0.f, 0.f, 0.f, 0.f};
      acc2[1] = (f32x4){0.f, 0.f, 0.f, 0.f};
#pragma unroll
      for (int ks = 0; ks < 8; ++ks) {
        int wo = w2base + dt * 4096 + ks * 512;
        s16x8 bh = *(const s16x8*)&w2ph[wo];
        s16x8 bl = *(const s16x8*)&w2pl[wo];
#pragma unroll
        for (int m2 = 0; m2 < 2; ++m2) {
          acc2[m2] = __builtin_amdgcn_mfma_f32_16x16x32_bf16(hh[m2][ks], bh, acc2[m2], 0, 0, 0);
          acc2[m2] = __builtin_amdgcn_mfma_f32_16x16x32_bf16(hh[m2][ks], bl, acc2[m2], 0, 0, 0);
          acc2[m2] = __builtin_amdgcn_mfma_f32_16x16x32_bf16(hl[m2][ks], bh, acc2[m2], 0, 0, 0);
        }
      }
      const int d2 = wv * 256 + dt * 16 + lo;
      float b2v = b2[(size_t)k * ND + d2];
#pragma unroll
      for (int m2 = 0; m2 < 2; ++m2)
#pragma unroll
        for (int i = 0; i < 4; ++i) {
          int row = (mc * 2 + m2) * 16 + quad * 4 + i;
          float rec = acc2[m2][i] + b2v;
          if (MODE == 2)
            reconb[((size_t)k * NB + r0 + row) * ND + d2] = f2bf(rec);
          float xv = x[(size_t)(r0 + row) * ND + d2];
          float dd = rec - xv;
          eacc[mc * 2 + m2][i] += dd * dd;
        }
    }
  }

  __syncthreads();   // all hs reads done before errp aliases the union
#pragma unroll
  for (int mt = 0; mt < 4; ++mt)
#pragma unroll
    for (int i = 0; i < 4; ++i) {
      float v = eacc[mt][i];
      v += __shfl_xor(v, 1, 16);
      v += __shfl_xor(v, 2, 16);
      v += __shfl_xor(v, 4, 16);
      v += __shfl_xor(v, 8, 16);
      if (lo == 0) s.errp[wv][mt * 16 + quad * 4 + i] = v;
    }
  __syncthreads();
  if (tid < 64)
    err[(size_t)k * NB + r0 + tid] =
        (s.errp[0][tid] + s.errp[1][tid] + s.errp[2][tid] + s.errp[3][tid]) * (1.0f / (float)ND);
}

// ---- argmin: winner expert per row (+ bucket for fallback paths)
__global__ __launch_bounds__(256) void ae_argmin(const float* __restrict__ err,
                                                 unsigned int* __restrict__ cnt,
                                                 int* __restrict__ bucket,
                                                 int* __restrict__ assign) {
  __shared__ unsigned int lc[KE];
  __shared__ unsigned int base[KE];
  int tid = threadIdx.x;
  if (tid < KE) lc[tid] = 0;
  __syncthreads();
  int b = blockIdx.x * 256 + tid;
  float best = err[b];
  int kmin = 0;
#pragma unroll
  for (int j = 1; j < KE; ++j) {
    float e = err[(size_t)j * NB + b];
    if (e < best) { best = e; kmin = j; }   // strict < == first-min (jnp.argmin)
  }
  assign[b] = kmin;
  unsigned int lpos = atomicAdd(&lc[kmin], 1u);
  __syncthreads();
  if (tid < KE) base[tid] = atomicAdd(&cnt[tid], lc[tid]);
  __syncthreads();
  bucket[(size_t)kmin * NB + (int)(base[kmin] + lpos)] = b;
}

// ---- gather (bf16 recon): out[b] = bf2f(reconb[assign[b]][b][:])
__global__ __launch_bounds__(256) void ae_gather_bf(
    const unsigned short* __restrict__ reconb,
    const int* __restrict__ assign, float* __restrict__ out) {
  const int b = blockIdx.x;
  const int kmin = assign[b];
  const unsigned short* src = &reconb[((size_t)kmin * NB + b) * ND];
  const int t = threadIdx.x;                // 256 threads x 4 elems = 1024
  u16x4 v = *(const u16x4*)&src[t * 4];
  float4 o;
  o.x = bf2f(v.x); o.y = bf2f(v.y); o.z = bf2f(v.z); o.w = bf2f(v.w);
  *(float4*)&out[(size_t)b * ND + t * 4] = o;
}

// ---- pass 2 FAST (fallback 1): h precomputed -> phase B only.
__global__ __launch_bounds__(256) void ae_pass2_fast(
    const unsigned short* __restrict__ hglob,
    const unsigned short* __restrict__ w2ph, const float* __restrict__ b2,
    const unsigned int* __restrict__ cnt, const int* __restrict__ bucket,
    float* __restrict__ out) {
  __shared__ int rid[64];

  const int k = blockIdx.x & 7;
  const int cv = (int)cnt[k];
  const int t0 = (blockIdx.x >> 3) * 64;
  if (t0 >= cv) return;                     // uniform exit before any barrier
  const int nrows = min(64, cv - t0);

  const int tid = threadIdx.x;
  const int wv = tid >> 6;
  const int lane = tid & 63;
  const int lo = lane & 15;
  const int quad = lane >> 4;

  if (tid < 64) {
    int idx = t0 + tid;
    rid[tid] = bucket[(size_t)k * NB + (idx < cv ? idx : t0)];
  }
  __syncthreads();

  const int grow = rid[wv * 16 + lo];       // this lane's winner row
  s16x8 af[8];                              // its 8 A-frag slices (32 VGPR)
  const size_t hbase = ((size_t)k * NB + grow) * NH + quad * 8;
#pragma unroll
  for (int ks = 0; ks < 8; ++ks)
    af[ks] = *(const s16x8*)&hglob[hbase + ks * 32];

  for (int c = 0; c < 32; ++c) {
    f32x4 acc2[2];
    acc2[0] = (f32x4){0.f, 0.f, 0.f, 0.f};
    acc2[1] = (f32x4){0.f, 0.f, 0.f, 0.f};
#pragma unroll
    for (int ks = 0; ks < 8; ++ks) {
#pragma unroll
      for (int nt = 0; nt < 2; ++nt) {
        s16x8 bfr = *(const s16x8*)&w2ph[(((size_t)(k * 64 + c * 2 + nt) * 8) + ks) * 512 + lane * 8];
        acc2[nt] = __builtin_amdgcn_mfma_f32_16x16x32_bf16(af[ks], bfr, acc2[nt], 0, 0, 0);
      }
    }
#pragma unroll
    for (int nt = 0; nt < 2; ++nt) {
      float b2v = b2[(size_t)k * ND + c * 32 + nt * 16 + lo];
#pragma unroll
      for (int i = 0; i < 4; ++i) {
        int row = wv * 16 + quad * 4 + i;
        if (row < nrows)
          out[(size_t)rid[row] * ND + c * 32 + nt * 16 + lo] = acc2[nt][i] + b2v;
      }
    }
  }
}

// ---- pass 2 (fallback 2, ws tiny): recompute winner rows from x
__global__ __launch_bounds__(256) void ae_pass2(
    const float* __restrict__ x,
    const unsigned short* __restrict__ w1ph, const float* __restrict__ b1,
    const unsigned short* __restrict__ w2ph, const float* __restrict__ b2,
    const unsigned int* __restrict__ cnt, const int* __restrict__ bucket,
    float* __restrict__ out) {
  __shared__ unsigned short hs[64][NH + 8];   // 33792 B
  __shared__ unsigned short xs[64][40];       // 5120 B
  __shared__ int rid[64];

  const int k = blockIdx.x & 7;
  const int cv = (int)cnt[k];
  const int t0 = (blockIdx.x >> 3) * 64;
  if (t0 >= cv) return;                     // uniform exit before any barrier
  const int nrows = min(64, cv - t0);

  const int tid = threadIdx.x;
  const int wv = tid >> 6;
  const int lane = tid & 63;
  const int lo = lane & 15;
  const int quad = lane >> 4;
  const int srow = tid >> 2, scol = (tid & 3) * 8;

  if (tid < 64) {
    int idx = t0 + tid;
    rid[tid] = bucket[(size_t)k * NB + (idx < cv ? idx : t0)];
  }
  __syncthreads();
  const int grow = rid[srow];

  f32x4 acc1[4][4];
#pragma unroll
  for (int mt = 0; mt < 4; ++mt)
#pragma unroll
    for (int nt = 0; nt < 4; ++nt) acc1[mt][nt] = (f32x4){0.f, 0.f, 0.f, 0.f};

  for (int it = 0; it < 32; ++it) {
    float4 xa = *(const float4*)&x[(size_t)grow * ND + it * 32 + scol];
    float4 xb = *(const float4*)&x[(size_t)grow * ND + it * 32 + scol + 4];
    s16x8 bfr[4];
#pragma unroll
    for (int nt = 0; nt < 4; ++nt)
      bfr[nt] = *(const s16x8*)&w1ph[(((size_t)(k * 16 + wv * 4 + nt) * 32) + it) * 512 + lane * 8];
    __syncthreads();   // prev frag reads done
    unsigned short t[8];
    t[0] = f2bf(xa.x); t[1] = f2bf(xa.y); t[2] = f2bf(xa.z); t[3] = f2bf(xa.w);
    t[4] = f2bf(xb.x); t[5] = f2bf(xb.y); t[6] = f2bf(xb.z); t[7] = f2bf(xb.w);
    *(u16x8*)&xs[srow][scol] = *(u16x8*)t;
    __syncthreads();
    s16x8 af[4];
#pragma unroll
    for (int mt = 0; mt < 4; ++mt) af[mt] = *(const s16x8*)&xs[mt * 16 + lo][quad * 8];
#pragma unroll
    for (int mt = 0; mt < 4; ++mt)
#pragma unroll
      for (int nt = 0; nt < 4; ++nt)
        acc1[mt][nt] = __builtin_amdgcn_mfma_f32_16x16x32_bf16(af[mt], bfr[nt], acc1[mt][nt], 0, 0, 0);
  }
  __syncthreads();

#pragma unroll
  for (int nt = 0; nt < 4; ++nt) {
    float b1v = b1[(size_t)k * NH + wv * 64 + nt * 16 + lo];
#pragma unroll
    for (int mt = 0; mt < 4; ++mt)
#pragma unroll
      for (int i = 0; i < 4; ++i) {
        float v = acc1[mt][nt][i] + b1v;
        v = v > 0.f ? v : 0.f;
        hs[mt * 16 + quad * 4 + i][wv * 64 + nt * 16 + lo] = f2bf(v);
      }
  }
  __syncthreads();

  // phase B: wave wv owns rows [wv*16, +16); d2 chunks of 32; no barriers.
  for (int c = 0; c < 32; ++c) {
    f32x4 acc2[2];
    acc2[0] = (f32x4){0.f, 0.f, 0.f, 0.f};
    acc2[1] = (f32x4){0.f, 0.f, 0.f, 0.f};
#pragma unroll
    for (int ks = 0; ks < 8; ++ks) {
      s16x8 af = *(const s16x8*)&hs[wv * 16 + lo][ks * 32 + quad * 8];
#pragma unroll
      for (int nt = 0; nt < 2; ++nt) {
        s16x8 bfr = *(const s16x8*)&w2ph[(((size_t)(k * 64 + c * 2 + nt) * 8) + ks) * 512 + lane * 8];
        acc2[nt] = __builtin_amdgcn_mfma_f32_16x16x32_bf16(af, bfr, acc2[nt], 0, 0, 0);
      }
    }
#pragma unroll
    for (int nt = 0; nt < 2; ++nt) {
      float b2v = b2[(size_t)k * ND + c * 32 + nt * 16 + lo];
#pragma unroll
      for (int i = 0; i < 4; ++i) {
        int row = wv * 16 + quad * 4 + i;
        if (row < nrows)
          out[(size_t)rid[row] * ND + c * 32 + nt * 16 + lo] = acc2[nt][i] + b2v;
      }
    }
  }
}

extern "C" void kernel_launch(void* const* d_in, const int* in_sizes, int n_in,
                              void* d_out, int out_size, void* d_ws, size_t ws_size,
                              hipStream_t stream) {
  (void)in_sizes; (void)n_in; (void)out_size;
  const float* x  = (const float*)d_in[0];
  const float* W1 = (const float*)d_in[1];
  const float* b1 = (const float*)d_in[2];
  const float* W2 = (const float*)d_in[3];
  const float* b2 = (const float*)d_in[4];
  float* out = (float*)d_out;

  char* ws = (char*)d_ws;
  const size_t szW = (size_t)KE * ND * NH * sizeof(unsigned short);  // 4 MB
  const size_t szX = (size_t)NB * ND * sizeof(unsigned short);       // 16.78 MB
  unsigned short* w1ph = (unsigned short*)(ws);
  unsigned short* w1pl = (unsigned short*)(ws + szW);
  unsigned short* w2ph = (unsigned short*)(ws + 2 * szW);
  unsigned short* w2pl = (unsigned short*)(ws + 3 * szW);
  unsigned short* xph  = (unsigned short*)(ws + 4 * szW);
  unsigned short* xpl  = (unsigned short*)(ws + 4 * szW + szX);
  char* tail           = ws + 4 * szW + 2 * szX;
  float* err           = (float*)tail;
  int* bucket          = (int*)(tail + (size_t)KE * NB * sizeof(float));
  unsigned int* cnt    = (unsigned int*)(tail + (size_t)KE * NB * sizeof(float)
                                         + (size_t)KE * NB * sizeof(int));
  int* assign          = (int*)(tail + (size_t)KE * NB * sizeof(float)
                                + (size_t)KE * NB * sizeof(int) + 4096);
  // base ~48.6 MB; tiers: reconb bf16 128MB (>= ~177MB) > hglob 32MB (>= ~81MB).
  size_t base = 4 * szW + 2 * szX + (size_t)KE * NB * (sizeof(float) + sizeof(int))
                + 4096 + (size_t)NB * sizeof(int) + 4096;
  size_t rbytes = (size_t)KE * NB * ND * sizeof(unsigned short);     // 128 MB
  size_t hbytes = (size_t)KE * NB * NH * sizeof(unsigned short);     // 32 MB
  unsigned short* reconb = (ws_size >= base + rbytes)
                               ? (unsigned short*)(ws + base) : nullptr;
  unsigned short* hglob = (!reconb && ws_size >= base + hbytes)
                              ? (unsigned short*)(ws + base) : nullptr;

  pack_all<<<6144, 256, 0, stream>>>(W1, w1ph, w1pl, W2, w2ph, w2pl, x, xph, xpl, cnt);
  if (reconb)
    ae_pass1_t<2><<<1024, 256, 0, stream>>>(xph, xpl, x, w1ph, w1pl, b1,
                                            w2ph, w2pl, b2, err, nullptr, reconb);
  else if (hglob)
    ae_pass1_t<1><<<1024, 256, 0, stream>>>(xph, xpl, x, w1ph, w1pl, b1,
                                            w2ph, w2pl, b2, err, hglob, nullptr);
  else
    ae_pass1_t<0><<<1024, 256, 0, stream>>>(xph, xpl, x, w1ph, w1pl, b1,
                                            w2ph, w2pl, b2, err, nullptr, nullptr);
  ae_argmin<<<NB / 256, 256, 0, stream>>>(err, cnt, bucket, assign);
  if (reconb)
    ae_gather_bf<<<NB, 256, 0, stream>>>(reconb, assign, out);
  else if (hglob)
    ae_pass2_fast<<<1024, 256, 0, stream>>>(hglob, w2ph, b2, cnt, bucket, out);
  else
    ae_pass2<<<1024, 256, 0, stream>>>(x, w1ph, b1, w2ph, b2, cnt, bucket, out);
}

// Round 13
// 350.990 us; speedup vs baseline: 1.2375x; 1.0599x over previous
//
#include <hip/hip_runtime.h>

// f32 I/O. K=8 expert AEs, B=8192, D=1024, H=256.
//   h = relu(x @ W1[k] + b1[k]); recon = h @ W2[k] + b2[k]
//   err[k,b] = mean((recon-x)^2); out[b] = recon[argmin_k err, b]
// CHAMPION = R17 (verified 372.0us): pass1 (2-stage reg dbuf phase A,
// h-in-regs phase B, [r_hi|k|r_lo] decode) + MODE2 bf16-recon store +
// argmin + gather. Dead ends: R8 ring (spill), R9 per-ks LDS (LDS-pipe),
// R11 cap (spill), R12 deeper pipe (-8%), R7/R13 global_load_lds (crash x2),
// R14 setprio (-7%), R16 runtime-branch store (+25us dead branch).
// R17 counters: WRITE 265MB = 2.07x the 128MB recon, FETCH +170MB -> the
// per-quad 32B half-line stores pay RMW fills; pass1 232->285us.
// R18 (this rev) = R17 + ONE change: PERMUTED reconb layout chosen from the
// writer's fragment geometry. Element index within (k,rtile) block:
//   ((((mc*2+m2)*16+dt)*4+i)*4+wv)*64 + lane
// -> each store instr writes 64 lanes x 2B = 128B contiguous (full lines,
// no RMW; same instruction count). Gather inverts the mapping (row fixes
// mcm2/quad/i; d fixes wv/dt/lo; u16x4 contiguous reads). Values unchanged.
// Tripwires: pass1 WRITE ~135MB/FETCH ~240MB expected; if WRITE stays
// ~265MB the RMW theory is wrong -> revert.

#define KE 8
#define NB 8192
#define ND 1024
#define NH 256

typedef float f32x4 __attribute__((ext_vector_type(4)));
typedef short s16x8 __attribute__((ext_vector_type(8)));
typedef unsigned short u16x8 __attribute__((ext_vector_type(8)));
typedef unsigned short u16x4 __attribute__((ext_vector_type(4)));

__device__ __forceinline__ float bf2f(unsigned short h) {
  union { unsigned int u; float f; } v; v.u = ((unsigned int)h) << 16; return v.f;
}
__device__ __forceinline__ unsigned short f2bf(float f) {
  union { unsigned int u; float f; } v; v.f = f;
  unsigned int u = v.u;
  u += 0x7fffu + ((u >> 16) & 1u);   // RTNE
  return (unsigned short)(u >> 16);
}
__device__ __forceinline__ void split2(float x, unsigned short& hi, unsigned short& lo) {
  hi = f2bf(x);
  lo = f2bf(x - bf2f(hi));
}

// ---- fused pack: W1, W2, x -> frag-ordered hi/lo arrays; also zeroes cnt.
__global__ __launch_bounds__(256) void pack_all(
    const float* __restrict__ W1, unsigned short* __restrict__ w1oh, unsigned short* __restrict__ w1ol,
    const float* __restrict__ W2, unsigned short* __restrict__ w2oh, unsigned short* __restrict__ w2ol,
    const float* __restrict__ xin, unsigned short* __restrict__ xoh, unsigned short* __restrict__ xol,
    unsigned int* __restrict__ cnt) {
  const int bx = blockIdx.x;
  const int tid = threadIdx.x;
  if (bx == 0 && tid < KE) cnt[tid] = 0;

  if (bx < 1024) {                           // ---- pack W1
    int gid = bx * 256 + tid;
    int L = gid & 63;
    int g = gid >> 6;
    int ks = g & 31;
    int ct = (g >> 5) & 15;
    int k = g >> 9;
    int col = ct * 16 + (L & 15);
    int kd0 = ks * 32 + (L >> 4) * 8;
    unsigned short th[8], tl[8];
#pragma unroll
    for (int j = 0; j < 8; ++j) {
      float v = W1[((size_t)k * ND + kd0 + j) * NH + col];
      split2(v, th[j], tl[j]);
    }
    size_t o = ((size_t)g * 64 + L) * 8;
    *(u16x8*)&w1oh[o] = *(u16x8*)th;
    *(u16x8*)&w1ol[o] = *(u16x8*)tl;
  } else if (bx < 2048) {                    // ---- pack W2
    int gid = (bx - 1024) * 256 + tid;
    int L = gid & 63;
    int g = gid >> 6;
    int ks = g & 7;
    int dt = (g >> 3) & 63;
    int k = g >> 9;
    int d2 = dt * 16 + (L & 15);
    int h0 = ks * 32 + (L >> 4) * 8;
    unsigned short th[8], tl[8];
#pragma unroll
    for (int j = 0; j < 8; ++j) {
      float v = W2[((size_t)k * NH + h0 + j) * ND + d2];
      split2(v, th[j], tl[j]);
    }
    size_t o = ((size_t)g * 64 + L) * 8;
    *(u16x8*)&w2oh[o] = *(u16x8*)th;
    *(u16x8*)&w2ol[o] = *(u16x8*)tl;
  } else {                                   // ---- pack x
    int gid = (bx - 2048) * 256 + tid;
    int L = gid & 63;
    int g = gid >> 6;
    int ks = g & 31;
    int rt = g >> 5;
    int row = rt * 16 + (L & 15);
    int kd0 = ks * 32 + (L >> 4) * 8;
    float4 a = *(const float4*)&xin[(size_t)row * ND + kd0];
    float4 b = *(const float4*)&xin[(size_t)row * ND + kd0 + 4];
    unsigned short th[8], tl[8];
    split2(a.x, th[0], tl[0]); split2(a.y, th[1], tl[1]);
    split2(a.z, th[2], tl[2]); split2(a.w, th[3], tl[3]);
    split2(b.x, th[4], tl[4]); split2(b.y, th[5], tl[5]);
    split2(b.z, th[6], tl[6]); split2(b.w, th[7], tl[7]);
    size_t o = ((size_t)g * 64 + L) * 8;
    *(u16x8*)&xoh[o] = *(u16x8*)th;
    *(u16x8*)&xol[o] = *(u16x8*)tl;
  }
}

// load one phase-A stage (16 frags, 256B/lane) into named register buffers
#define LOAD_STAGE(ah, al, bh, bl, it)                  \
  do {                                                  \
    _Pragma("unroll")                                   \
    for (int q_ = 0; q_ < 4; ++q_) {                    \
      int o_ = xo[q_] + (it) * 512;                     \
      ah[q_] = *(const s16x8*)&xph[o_];                 \
      al[q_] = *(const s16x8*)&xpl[o_];                 \
    }                                                   \
    _Pragma("unroll")                                   \
    for (int q_ = 0; q_ < 4; ++q_) {                    \
      int o_ = wo1[q_] + (it) * 512;                    \
      bh[q_] = *(const s16x8*)&w1ph[o_];                \
      bl[q_] = *(const s16x8*)&w1pl[o_];                \
    }                                                   \
  } while (0)

// 48 MFMAs (3-product split) on one stage
#define MFMA_STAGE(ah, al, bh, bl)                                                                   \
  do {                                                                                               \
    _Pragma("unroll")                                                                                \
    for (int nt_ = 0; nt_ < 4; ++nt_)                                                                \
      _Pragma("unroll")                                                                              \
      for (int mt_ = 0; mt_ < 4; ++mt_) {                                                            \
        acc1[mt_][nt_] = __builtin_amdgcn_mfma_f32_16x16x32_bf16(ah[mt_], bh[nt_], acc1[mt_][nt_], 0, 0, 0); \
        acc1[mt_][nt_] = __builtin_amdgcn_mfma_f32_16x16x32_bf16(ah[mt_], bl[nt_], acc1[mt_][nt_], 0, 0, 0); \
        acc1[mt_][nt_] = __builtin_amdgcn_mfma_f32_16x16x32_bf16(al[mt_], bh[nt_], acc1[mt_][nt_], 0, 0, 0); \
      }                                                                                              \
  } while (0)

// ---- pass 1: split-precision err[K][B]. BM=64, grid 1024.
// Champion decode: bx bits [r_hi | k(3b) | r_lo(3b)].
// MODE (compile-time): 0 = no aux store; 1 = hglob store (R15); 2 = bf16
// recon store in writer-friendly PERMUTED layout. No hot runtime branches.
template <int MODE>
__global__ __launch_bounds__(256, 2) void ae_pass1_t(
    const unsigned short* __restrict__ xph, const unsigned short* __restrict__ xpl,
    const float* __restrict__ x,
    const unsigned short* __restrict__ w1ph, const unsigned short* __restrict__ w1pl,
    const float* __restrict__ b1,
    const unsigned short* __restrict__ w2ph, const unsigned short* __restrict__ w2pl,
    const float* __restrict__ b2, float* __restrict__ err,
    unsigned short* __restrict__ hglob, unsigned short* __restrict__ reconb) {
  __shared__ union {
    struct { unsigned short h[64][256]; unsigned short l[64][256]; } hs;  // 65536 B
    float errp[4][64];
  } s;

  const int tid = threadIdx.x;
  const int wv = tid >> 6;
  const int lane = tid & 63;
  const int lo = lane & 15;
  const int quad = lane >> 4;
  const int k = (blockIdx.x >> 3) & 7;
  const int rtile = (int)(((blockIdx.x >> 6) << 3) | (blockIdx.x & 7));
  const int r0 = rtile * 64;

  // ---------- phase A: h = relu(x@W1+b1). Barrier-free, register-pipelined.
  int xo[4], wo1[4];
#pragma unroll
  for (int mt = 0; mt < 4; ++mt) xo[mt] = ((rtile * 4 + mt) * 32) * 512 + lane * 8;
#pragma unroll
  for (int nt = 0; nt < 4; ++nt) wo1[nt] = ((k * 16 + wv * 4 + nt) * 32) * 512 + lane * 8;

  f32x4 acc1[4][4];
#pragma unroll
  for (int mt = 0; mt < 4; ++mt)
#pragma unroll
    for (int nt = 0; nt < 4; ++nt) acc1[mt][nt] = (f32x4){0.f, 0.f, 0.f, 0.f};

  s16x8 Aah[4], Aal[4], Abh[4], Abl[4];
  s16x8 Bah[4], Bal[4], Bbh[4], Bbl[4];
  LOAD_STAGE(Aah, Aal, Abh, Abl, 0);
  LOAD_STAGE(Bah, Bal, Bbh, Bbl, 1);
  for (int it = 0; it < 32; it += 2) {
    MFMA_STAGE(Aah, Aal, Abh, Abl);
    if (it + 2 < 32) LOAD_STAGE(Aah, Aal, Abh, Abl, it + 2);
    MFMA_STAGE(Bah, Bal, Bbh, Bbl);
    if (it + 3 < 32) LOAD_STAGE(Bah, Bal, Bbh, Bbl, it + 3);
  }

  // epilogue A: +b1, relu, split h -> LDS swizzled; MODE1: also store h.
#pragma unroll
  for (int nt = 0; nt < 4; ++nt) {
    float b1v = b1[(size_t)k * NH + wv * 64 + nt * 16 + lo];
#pragma unroll
    for (int mt = 0; mt < 4; ++mt)
#pragma unroll
      for (int i = 0; i < 4; ++i) {
        float v = acc1[mt][nt][i] + b1v;
        v = v > 0.f ? v : 0.f;
        unsigned short vh, vl;
        split2(v, vh, vl);
        int row = mt * 16 + quad * 4 + i, col = wv * 64 + nt * 16 + lo;
        int sc = col ^ ((row & 7) << 3);
        s.hs.h[row][sc] = vh;
        s.hs.l[row][sc] = vl;
        if (MODE == 1) hglob[((size_t)k * NB + r0 + row) * NH + col] = vh;
      }
  }
  __syncthreads();   // the ONE inter-phase barrier

  // ---------- phase B: recon = h@W2+b2. Wave wv owns d2-strip [wv*256, +256).
  // h A-frags dt-invariant: 2-row-tile chunk in regs, W2 streamed.
  // MODE2: store split recon (bf16) in permuted layout -> 128B/instr stores.
  float eacc[4][4];
#pragma unroll
  for (int mt = 0; mt < 4; ++mt)
#pragma unroll
    for (int i = 0; i < 4; ++i) eacc[mt][i] = 0.f;

  const int w2base = ((k * 64 + wv * 16) * 8) * 512 + lane * 8;
  const size_t rcbase = ((size_t)k * NB + (size_t)r0) * ND;   // block region

  for (int mc = 0; mc < 2; ++mc) {
    s16x8 hh[2][8], hl[2][8];
#pragma unroll
    for (int m2 = 0; m2 < 2; ++m2) {
      int row = (mc * 2 + m2) * 16 + lo;
      int rbase = row * 256;
      int sw = (row & 7) << 3;
#pragma unroll
      for (int ks = 0; ks < 8; ++ks) {
        int off = rbase + ((ks * 32 + quad * 8) ^ sw);
        hh[m2][ks] = *(const s16x8*)(&s.hs.h[0][0] + off);
        hl[m2][ks] = *(const s16x8*)(&s.hs.l[0][0] + off);
      }
    }
    for (int dt = 0; dt < 16; ++dt) {
      f32x4 acc2[2];
      acc2[0] = (f32x4){0.f, 0.f, 0.f, 0.f};
      acc2[1] = (f32x4){0.f, 0.f, 0.f, 0.f};
#pragma unroll
      for (int ks = 0; ks < 8; ++ks) {
        int wo = w2base + dt * 4096 + ks * 512;
        s16x8 bh = *(const s16x8*)&w2ph[wo];
        s16x8 bl = *(const s16x8*)&w2pl[wo];
#pragma unroll
        for (int m2 = 0; m2 < 2; ++m2) {
          acc2[m2] = __builtin_amdgcn_mfma_f32_16x16x32_bf16(hh[m2][ks], bh, acc2[m2], 0, 0, 0);
          acc2[m2] = __builtin_amdgcn_mfma_f32_16x16x32_bf16(hh[m2][ks], bl, acc2[m2], 0, 0, 0);
          acc2[m2] = __builtin_amdgcn_mfma_f32_16x16x32_bf16(hl[m2][ks], bh, acc2[m2], 0, 0, 0);
        }
      }
      const int d2 = wv * 256 + dt * 16 + lo;
      float b2v = b2[(size_t)k * ND + d2];
#pragma unroll
      for (int m2 = 0; m2 < 2; ++m2)
#pragma unroll
        for (int i = 0; i < 4; ++i) {
          int row = (mc * 2 + m2) * 16 + quad * 4 + i;
          float rec = acc2[m2][i] + b2v;
          if (MODE == 2) {
            // permuted: ((((mc*2+m2)*16+dt)*4+i)*4+wv)*64 + lane  -> 128B/instr
            size_t off = rcbase +
                (size_t)(((((mc * 2 + m2) * 16 + dt) * 4 + i) * 4 + wv) * 64 + lane);
            reconb[off] = f2bf(rec);
          }
          float xv = x[(size_t)(r0 + row) * ND + d2];
          float dd = rec - xv;
          eacc[mc * 2 + m2][i] += dd * dd;
        }
    }
  }

  __syncthreads();   // all hs reads done before errp aliases the union
#pragma unroll
  for (int mt = 0; mt < 4; ++mt)
#pragma unroll
    for (int i = 0; i < 4; ++i) {
      float v = eacc[mt][i];
      v += __shfl_xor(v, 1, 16);
      v += __shfl_xor(v, 2, 16);
      v += __shfl_xor(v, 4, 16);
      v += __shfl_xor(v, 8, 16);
      if (lo == 0) s.errp[wv][mt * 16 + quad * 4 + i] = v;
    }
  __syncthreads();
  if (tid < 64)
    err[(size_t)k * NB + r0 + tid] =
        (s.errp[0][tid] + s.errp[1][tid] + s.errp[2][tid] + s.errp[3][tid]) * (1.0f / (float)ND);
}

// ---- argmin: winner expert per row (+ bucket for fallback paths)
__global__ __launch_bounds__(256) void ae_argmin(const float* __restrict__ err,
                                                 unsigned int* __restrict__ cnt,
                                                 int* __restrict__ bucket,
                                                 int* __restrict__ assign) {
  __shared__ unsigned int lc[KE];
  __shared__ unsigned int base[KE];
  int tid = threadIdx.x;
  if (tid < KE) lc[tid] = 0;
  __syncthreads();
  int b = blockIdx.x * 256 + tid;
  float best = err[b];
  int kmin = 0;
#pragma unroll
  for (int j = 1; j < KE; ++j) {
    float e = err[(size_t)j * NB + b];
    if (e < best) { best = e; kmin = j; }   // strict < == first-min (jnp.argmin)
  }
  assign[b] = kmin;
  unsigned int lpos = atomicAdd(&lc[kmin], 1u);
  __syncthreads();
  if (tid < KE) base[tid] = atomicAdd(&cnt[tid], lc[tid]);
  __syncthreads();
  bucket[(size_t)kmin * NB + (int)(base[kmin] + lpos)] = b;
}

// ---- gather (permuted bf16 recon): out[b][d] = bf2f(reconb[map(b,d)])
// map: block (k, rtile=b>>6); row=b&63 -> mcm2=row>>4, quad=(row>>2)&3, i=row&3;
// d -> wv=d>>8, dt=(d>>4)&15, lo=d&15; lane=quad*16+lo;
// elem = ((k*NB + rtile*64)*ND) + (((mcm2*16+dt)*4+i)*4+wv)*64 + lane.
__global__ __launch_bounds__(256) void ae_gather_bf(
    const unsigned short* __restrict__ reconb,
    const int* __restrict__ assign, float* __restrict__ out) {
  const int b = blockIdx.x;
  const int kmin = assign[b];
  const int row = b & 63;
  const int mcm2 = row >> 4, quad = (row >> 2) & 3, i = row & 3;
  const size_t rcbase = ((size_t)kmin * NB + (size_t)(b & ~63)) * ND;
  const int t = threadIdx.x;
  const int d0 = t * 4;                      // 4 elems/thread, same (wv,dt)
  const int wv = d0 >> 8, dt = (d0 >> 4) & 15, lo = d0 & 15;
  const int lane = quad * 16 + lo;
  size_t off = rcbase + (size_t)((((mcm2 * 16 + dt) * 4 + i) * 4 + wv) * 64 + lane);
  u16x4 v = *(const u16x4*)&reconb[off];
  float4 o;
  o.x = bf2f(v.x); o.y = bf2f(v.y); o.z = bf2f(v.z); o.w = bf2f(v.w);
  *(float4*)&out[(size_t)b * ND + d0] = o;
}

// ---- pass 2 FAST (fallback 1): h precomputed -> phase B only.
__global__ __launch_bounds__(256) void ae_pass2_fast(
    const unsigned short* __restrict__ hglob,
    const unsigned short* __restrict__ w2ph, const float* __restrict__ b2,
    const unsigned int* __restrict__ cnt, const int* __restrict__ bucket,
    float* __restrict__ out) {
  __shared__ int rid[64];

  const int k = blockIdx.x & 7;
  const int cv = (int)cnt[k];
  const int t0 = (blockIdx.x >> 3) * 64;
  if (t0 >= cv) return;                     // uniform exit before any barrier
  const int nrows = min(64, cv - t0);

  const int tid = threadIdx.x;
  const int wv = tid >> 6;
  const int lane = tid & 63;
  const int lo = lane & 15;
  const int quad = lane >> 4;

  if (tid < 64) {
    int idx = t0 + tid;
    rid[tid] = bucket[(size_t)k * NB + (idx < cv ? idx : t0)];
  }
  __syncthreads();

  const int grow = rid[wv * 16 + lo];       // this lane's winner row
  s16x8 af[8];                              // its 8 A-frag slices (32 VGPR)
  const size_t hbase = ((size_t)k * NB + grow) * NH + quad * 8;
#pragma unroll
  for (int ks = 0; ks < 8; ++ks)
    af[ks] = *(const s16x8*)&hglob[hbase + ks * 32];

  for (int c = 0; c < 32; ++c) {
    f32x4 acc2[2];
    acc2[0] = (f32x4){0.f, 0.f, 0.f, 0.f};
    acc2[1] = (f32x4){0.f, 0.f, 0.f, 0.f};
#pragma unroll
    for (int ks = 0; ks < 8; ++ks) {
#pragma unroll
      for (int nt = 0; nt < 2; ++nt) {
        s16x8 bfr = *(const s16x8*)&w2ph[(((size_t)(k * 64 + c * 2 + nt) * 8) + ks) * 512 + lane * 8];
        acc2[nt] = __builtin_amdgcn_mfma_f32_16x16x32_bf16(af[ks], bfr, acc2[nt], 0, 0, 0);
      }
    }
#pragma unroll
    for (int nt = 0; nt < 2; ++nt) {
      float b2v = b2[(size_t)k * ND + c * 32 + nt * 16 + lo];
#pragma unroll
      for (int i = 0; i < 4; ++i) {
        int row = wv * 16 + quad * 4 + i;
        if (row < nrows)
          out[(size_t)rid[row] * ND + c * 32 + nt * 16 + lo] = acc2[nt][i] + b2v;
      }
    }
  }
}

// ---- pass 2 (fallback 2, ws tiny): recompute winner rows from x
__global__ __launch_bounds__(256) void ae_pass2(
    const float* __restrict__ x,
    const unsigned short* __restrict__ w1ph, const float* __restrict__ b1,
    const unsigned short* __restrict__ w2ph, const float* __restrict__ b2,
    const unsigned int* __restrict__ cnt, const int* __restrict__ bucket,
    float* __restrict__ out) {
  __shared__ unsigned short hs[64][NH + 8];   // 33792 B
  __shared__ unsigned short xs[64][40];       // 5120 B
  __shared__ int rid[64];

  const int k = blockIdx.x & 7;
  const int cv = (int)cnt[k];
  const int t0 = (blockIdx.x >> 3) * 64;
  if (t0 >= cv) return;                     // uniform exit before any barrier
  const int nrows = min(64, cv - t0);

  const int tid = threadIdx.x;
  const int wv = tid >> 6;
  const int lane = tid & 63;
  const int lo = lane & 15;
  const int quad = lane >> 4;
  const int srow = tid >> 2, scol = (tid & 3) * 8;

  if (tid < 64) {
    int idx = t0 + tid;
    rid[tid] = bucket[(size_t)k * NB + (idx < cv ? idx : t0)];
  }
  __syncthreads();
  const int grow = rid[srow];

  f32x4 acc1[4][4];
#pragma unroll
  for (int mt = 0; mt < 4; ++mt)
#pragma unroll
    for (int nt = 0; nt < 4; ++nt) acc1[mt][nt] = (f32x4){0.f, 0.f, 0.f, 0.f};

  for (int it = 0; it < 32; ++it) {
    float4 xa = *(const float4*)&x[(size_t)grow * ND + it * 32 + scol];
    float4 xb = *(const float4*)&x[(size_t)grow * ND + it * 32 + scol + 4];
    s16x8 bfr[4];
#pragma unroll
    for (int nt = 0; nt < 4; ++nt)
      bfr[nt] = *(const s16x8*)&w1ph[(((size_t)(k * 16 + wv * 4 + nt) * 32) + it) * 512 + lane * 8];
    __syncthreads();   // prev frag reads done
    unsigned short t[8];
    t[0] = f2bf(xa.x); t[1] = f2bf(xa.y); t[2] = f2bf(xa.z); t[3] = f2bf(xa.w);
    t[4] = f2bf(xb.x); t[5] = f2bf(xb.y); t[6] = f2bf(xb.z); t[7] = f2bf(xb.w);
    *(u16x8*)&xs[srow][scol] = *(u16x8*)t;
    __syncthreads();
    s16x8 af[4];
#pragma unroll
    for (int mt = 0; mt < 4; ++mt) af[mt] = *(const s16x8*)&xs[mt * 16 + lo][quad * 8];
#pragma unroll
    for (int mt = 0; mt < 4; ++mt)
#pragma unroll
      for (int nt = 0; nt < 4; ++nt)
        acc1[mt][nt] = __builtin_amdgcn_mfma_f32_16x16x32_bf16(af[mt], bfr[nt], acc1[mt][nt], 0, 0, 0);
  }
  __syncthreads();

#pragma unroll
  for (int nt = 0; nt < 4; ++nt) {
    float b1v = b1[(size_t)k * NH + wv * 64 + nt * 16 + lo];
#pragma unroll
    for (int mt = 0; mt < 4; ++mt)
#pragma unroll
      for (int i = 0; i < 4; ++i) {
        float v = acc1[mt][nt][i] + b1v;
        v = v > 0.f ? v : 0.f;
        hs[mt * 16 + quad * 4 + i][wv * 64 + nt * 16 + lo] = f2bf(v);
      }
  }
  __syncthreads();

  // phase B: wave wv owns rows [wv*16, +16); d2 chunks of 32; no barriers.
  for (int c = 0; c < 32; ++c) {
    f32x4 acc2[2];
    acc2[0] = (f32x4){0.f, 0.f, 0.f, 0.f};
    acc2[1] = (f32x4){0.f, 0.f, 0.f, 0.f};
#pragma unroll
    for (int ks = 0; ks < 8; ++ks) {
      s16x8 af = *(const s16x8*)&hs[wv * 16 + lo][ks * 32 + quad * 8];
#pragma unroll
      for (int nt = 0; nt < 2; ++nt) {
        s16x8 bfr = *(const s16x8*)&w2ph[(((size_t)(k * 64 + c * 2 + nt) * 8) + ks) * 512 + lane * 8];
        acc2[nt] = __builtin_amdgcn_mfma_f32_16x16x32_bf16(af, bfr, acc2[nt], 0, 0, 0);
      }
    }
#pragma unroll
    for (int nt = 0; nt < 2; ++nt) {
      float b2v = b2[(size_t)k * ND + c * 32 + nt * 16 + lo];
#pragma unroll
      for (int i = 0; i < 4; ++i) {
        int row = wv * 16 + quad * 4 + i;
        if (row < nrows)
          out[(size_t)rid[row] * ND + c * 32 + nt * 16 + lo] = acc2[nt][i] + b2v;
      }
    }
  }
}

extern "C" void kernel_launch(void* const* d_in, const int* in_sizes, int n_in,
                              void* d_out, int out_size, void* d_ws, size_t ws_size,
                              hipStream_t stream) {
  (void)in_sizes; (void)n_in; (void)out_size;
  const float* x  = (const float*)d_in[0];
  const float* W1 = (const float*)d_in[1];
  const float* b1 = (const float*)d_in[2];
  const float* W2 = (const float*)d_in[3];
  const float* b2 = (const float*)d_in[4];
  float* out = (float*)d_out;

  char* ws = (char*)d_ws;
  const size_t szW = (size_t)KE * ND * NH * sizeof(unsigned short);  // 4 MB
  const size_t szX = (size_t)NB * ND * sizeof(unsigned short);       // 16.78 MB
  unsigned short* w1ph = (unsigned short*)(ws);
  unsigned short* w1pl = (unsigned short*)(ws + szW);
  unsigned short* w2ph = (unsigned short*)(ws + 2 * szW);
  unsigned short* w2pl = (unsigned short*)(ws + 3 * szW);
  unsigned short* xph  = (unsigned short*)(ws + 4 * szW);
  unsigned short* xpl  = (unsigned short*)(ws + 4 * szW + szX);
  char* tail           = ws + 4 * szW + 2 * szX;
  float* err           = (float*)tail;
  int* bucket          = (int*)(tail + (size_t)KE * NB * sizeof(float));
  unsigned int* cnt    = (unsigned int*)(tail + (size_t)KE * NB * sizeof(float)
                                         + (size_t)KE * NB * sizeof(int));
  int* assign          = (int*)(tail + (size_t)KE * NB * sizeof(float)
                                + (size_t)KE * NB * sizeof(int) + 4096);
  // base ~48.6 MB; tiers: reconb bf16 128MB (>= ~177MB) > hglob 32MB (>= ~81MB).
  size_t base = 4 * szW + 2 * szX + (size_t)KE * NB * (sizeof(float) + sizeof(int))
                + 4096 + (size_t)NB * sizeof(int) + 4096;
  size_t rbytes = (size_t)KE * NB * ND * sizeof(unsigned short);     // 128 MB
  size_t hbytes = (size_t)KE * NB * NH * sizeof(unsigned short);     // 32 MB
  unsigned short* reconb = (ws_size >= base + rbytes)
                               ? (unsigned short*)(ws + base) : nullptr;
  unsigned short* hglob = (!reconb && ws_size >= base + hbytes)
                              ? (unsigned short*)(ws + base) : nullptr;

  pack_all<<<6144, 256, 0, stream>>>(W1, w1ph, w1pl, W2, w2ph, w2pl, x, xph, xpl, cnt);
  if (reconb)
    ae_pass1_t<2><<<1024, 256, 0, stream>>>(xph, xpl, x, w1ph, w1pl, b1,
                                            w2ph, w2pl, b2, err, nullptr, reconb);
  else if (hglob)
    ae_pass1_t<1><<<1024, 256, 0, stream>>>(xph, xpl, x, w1ph, w1pl, b1,
                                            w2ph, w2pl, b2, err, hglob, nullptr);
  else
    ae_pass1_t<0><<<1024, 256, 0, stream>>>(xph, xpl, x, w1ph, w1pl, b1,
                                            w2ph, w2pl, b2, err, nullptr, nullptr);
  ae_argmin<<<NB / 256, 256, 0, stream>>>(err, cnt, bucket, assign);
  if (reconb)
    ae_gather_bf<<<NB, 256, 0, stream>>>(reconb, assign, out);
  else if (hglob)
    ae_pass2_fast<<<1024, 256, 0, stream>>>(hglob, w2ph, b2, cnt, bucket, out);
  else
    ae_pass2<<<1024, 256, 0, stream>>>(x, w1ph, b1, w2ph, b2, cnt, bucket, out);
}

// Round 14
// 346.851 us; speedup vs baseline: 1.2523x; 1.0119x over previous
//
#include <hip/hip_runtime.h>

// f32 I/O. K=8 expert AEs, B=8192, D=1024, H=256.
//   h = relu(x @ W1[k] + b1[k]); recon = h @ W2[k] + b2[k]
//   err[k,b] = mean((recon-x)^2); out[b] = recon[argmin_k err, b]
// CHAMPION = R18 (verified 351.0us): pass1 (2-stage reg dbuf phase A,
// h-in-regs phase B, [r_hi|k|r_lo] decode) + MODE2 bf16-recon store in
// PERMUTED writer-friendly layout (128B/instr stores, WRITE 265->128MB
// confirmed) + argmin + inverse-mapped gather.
// Dead ends: R8 ring (spill), R9-pass1 per-ks LDS (LDS-pipe), R11 cap
// (spill), R12 deeper pipe (-8%), R7/R13 global_load_lds (crash x2),
// R14 setprio (-7%), R16 runtime-branch store (+25us).
// pass1 floor: 232us latency-pinned at 2 waves/SIMD + ~10us recon store.
// R19 (this rev) = exact R18 + ISOLATED pack rewrite (the R9 pack, which
// passed correctness but was confounded by R9's pass1 changes):
//   W1/W2 pack via coalesced float4 row reads -> LDS[32][260] transpose ->
//   fragment emit with 1KB coalesced stores. Replaces 2M scalar 4B loads
//   at 1KB stride. x-pack unchanged. Single change; pass1 untouched.
// Tripwire: total improves <10us -> pack wasn't dominant; fuse argmin+gather
// next or declare plateau.

#define KE 8
#define NB 8192
#define ND 1024
#define NH 256

typedef float f32x4 __attribute__((ext_vector_type(4)));
typedef short s16x8 __attribute__((ext_vector_type(8)));
typedef unsigned short u16x8 __attribute__((ext_vector_type(8)));
typedef unsigned short u16x4 __attribute__((ext_vector_type(4)));

__device__ __forceinline__ float bf2f(unsigned short h) {
  union { unsigned int u; float f; } v; v.u = ((unsigned int)h) << 16; return v.f;
}
__device__ __forceinline__ unsigned short f2bf(float f) {
  union { unsigned int u; float f; } v; v.f = f;
  unsigned int u = v.u;
  u += 0x7fffu + ((u >> 16) & 1u);   // RTNE
  return (unsigned short)(u >> 16);
}
__device__ __forceinline__ void split2(float x, unsigned short& hi, unsigned short& lo) {
  hi = f2bf(x);
  lo = f2bf(x - bf2f(hi));
}

// ---- fused pack: W1/W2 via LDS-transpose (coalesced), x direct; zeroes cnt.
// blocks [0,256):    W1 tile (k=b>>5, ks=b&31): rows ks*32..+32 of [1024][256]
// blocks [256,512):  W2 tile (k=b>>5, ks=(b>>2)&7, q=b&3): rows ks*32..+32,
//                    cols q*256..+256 of [256][1024]
// blocks [512,4608): x frag g=rt*32+ks (direct, already coalesced)
__global__ __launch_bounds__(256) void pack_all(
    const float* __restrict__ W1, unsigned short* __restrict__ w1oh, unsigned short* __restrict__ w1ol,
    const float* __restrict__ W2, unsigned short* __restrict__ w2oh, unsigned short* __restrict__ w2ol,
    const float* __restrict__ xin, unsigned short* __restrict__ xoh, unsigned short* __restrict__ xol,
    unsigned int* __restrict__ cnt) {
  __shared__ float t[32][260];   // 33.3 KB; +4 pad per row
  const int bx = blockIdx.x;
  const int tid = threadIdx.x;
  if (bx == 0 && tid < KE) cnt[tid] = 0;

  if (bx < 512) {
    // ---- W matrices via LDS transpose
    const bool isW1 = bx < 256;
    const int b = isW1 ? bx : bx - 256;
    int k, ks, q, CLEN, rowbase, c0;
    const float* src;
    unsigned short *oh, *ol;
    if (isW1) {
      k = b >> 5; ks = b & 31; q = 0;
      CLEN = 256; rowbase = k * ND + ks * 32; c0 = 0;
      src = W1; oh = w1oh; ol = w1ol;
    } else {
      k = b >> 5; ks = (b >> 2) & 7; q = b & 3;
      CLEN = 1024; rowbase = k * NH + ks * 32; c0 = q * 256;
      src = W2; oh = w2oh; ol = w2ol;
    }
    // stage 32 rows x 256 cols, coalesced float4 (64 float4 per row)
#pragma unroll
    for (int tl = 0; tl < 8; ++tl) {
      int idx = tl * 256 + tid;          // 2048 float4 slots
      int r = idx >> 6;
      int c4 = (idx & 63) * 4;
      float4 v = *(const float4*)&src[(size_t)(rowbase + r) * CLEN + c0 + c4];
      *(float4*)&t[r][c4] = v;           // contiguous b128 -> conflict-free
    }
    __syncthreads();
    // emit 16 ct-tiles x 64 lanes = 1024 frag slots, 4 per thread
#pragma unroll
    for (int tl = 0; tl < 4; ++tl) {
      int slot = tl * 256 + tid;
      int ct = slot >> 6, l = slot & 63;
      unsigned short th[8], tlw[8];
#pragma unroll
      for (int j = 0; j < 8; ++j)
        split2(t[(l >> 4) * 8 + j][ct * 16 + (l & 15)], th[j], tlw[j]);
      size_t g = isW1 ? ((size_t)(k * 16 + ct) * 32 + ks)
                      : ((size_t)(k * 64 + q * 16 + ct) * 8 + ks);
      size_t o = (g * 64 + l) * 8;
      *(u16x8*)&oh[o] = *(u16x8*)th;
      *(u16x8*)&ol[o] = *(u16x8*)tlw;
    }
  } else {                                   // ---- pack x (direct)
    int gid = (bx - 512) * 256 + tid;        // 1048576
    int L = gid & 63;
    int g = gid >> 6;
    int ks = g & 31;
    int rt = g >> 5;
    int row = rt * 16 + (L & 15);
    int kd0 = ks * 32 + (L >> 4) * 8;
    float4 a = *(const float4*)&xin[(size_t)row * ND + kd0];
    float4 b4 = *(const float4*)&xin[(size_t)row * ND + kd0 + 4];
    unsigned short th[8], tlw[8];
    split2(a.x, th[0], tlw[0]); split2(a.y, th[1], tlw[1]);
    split2(a.z, th[2], tlw[2]); split2(a.w, th[3], tlw[3]);
    split2(b4.x, th[4], tlw[4]); split2(b4.y, th[5], tlw[5]);
    split2(b4.z, th[6], tlw[6]); split2(b4.w, th[7], tlw[7]);
    size_t o = ((size_t)g * 64 + L) * 8;
    *(u16x8*)&xoh[o] = *(u16x8*)th;
    *(u16x8*)&xol[o] = *(u16x8*)tlw;
  }
}

// load one phase-A stage (16 frags, 256B/lane) into named register buffers
#define LOAD_STAGE(ah, al, bh, bl, it)                  \
  do {                                                  \
    _Pragma("unroll")                                   \
    for (int q_ = 0; q_ < 4; ++q_) {                    \
      int o_ = xo[q_] + (it) * 512;                     \
      ah[q_] = *(const s16x8*)&xph[o_];                 \
      al[q_] = *(const s16x8*)&xpl[o_];                 \
    }                                                   \
    _Pragma("unroll")                                   \
    for (int q_ = 0; q_ < 4; ++q_) {                    \
      int o_ = wo1[q_] + (it) * 512;                    \
      bh[q_] = *(const s16x8*)&w1ph[o_];                \
      bl[q_] = *(const s16x8*)&w1pl[o_];                \
    }                                                   \
  } while (0)

// 48 MFMAs (3-product split) on one stage
#define MFMA_STAGE(ah, al, bh, bl)                                                                   \
  do {                                                                                               \
    _Pragma("unroll")                                                                                \
    for (int nt_ = 0; nt_ < 4; ++nt_)                                                                \
      _Pragma("unroll")                                                                              \
      for (int mt_ = 0; mt_ < 4; ++mt_) {                                                            \
        acc1[mt_][nt_] = __builtin_amdgcn_mfma_f32_16x16x32_bf16(ah[mt_], bh[nt_], acc1[mt_][nt_], 0, 0, 0); \
        acc1[mt_][nt_] = __builtin_amdgcn_mfma_f32_16x16x32_bf16(ah[mt_], bl[nt_], acc1[mt_][nt_], 0, 0, 0); \
        acc1[mt_][nt_] = __builtin_amdgcn_mfma_f32_16x16x32_bf16(al[mt_], bh[nt_], acc1[mt_][nt_], 0, 0, 0); \
      }                                                                                              \
  } while (0)

// ---- pass 1: split-precision err[K][B]. BM=64, grid 1024.
// Champion decode: bx bits [r_hi | k(3b) | r_lo(3b)].
// MODE (compile-time): 0 = no aux store; 1 = hglob store; 2 = bf16 recon
// store in writer-friendly PERMUTED layout. No hot runtime branches.
template <int MODE>
__global__ __launch_bounds__(256, 2) void ae_pass1_t(
    const unsigned short* __restrict__ xph, const unsigned short* __restrict__ xpl,
    const float* __restrict__ x,
    const unsigned short* __restrict__ w1ph, const unsigned short* __restrict__ w1pl,
    const float* __restrict__ b1,
    const unsigned short* __restrict__ w2ph, const unsigned short* __restrict__ w2pl,
    const float* __restrict__ b2, float* __restrict__ err,
    unsigned short* __restrict__ hglob, unsigned short* __restrict__ reconb) {
  __shared__ union {
    struct { unsigned short h[64][256]; unsigned short l[64][256]; } hs;  // 65536 B
    float errp[4][64];
  } s;

  const int tid = threadIdx.x;
  const int wv = tid >> 6;
  const int lane = tid & 63;
  const int lo = lane & 15;
  const int quad = lane >> 4;
  const int k = (blockIdx.x >> 3) & 7;
  const int rtile = (int)(((blockIdx.x >> 6) << 3) | (blockIdx.x & 7));
  const int r0 = rtile * 64;

  // ---------- phase A: h = relu(x@W1+b1). Barrier-free, register-pipelined.
  int xo[4], wo1[4];
#pragma unroll
  for (int mt = 0; mt < 4; ++mt) xo[mt] = ((rtile * 4 + mt) * 32) * 512 + lane * 8;
#pragma unroll
  for (int nt = 0; nt < 4; ++nt) wo1[nt] = ((k * 16 + wv * 4 + nt) * 32) * 512 + lane * 8;

  f32x4 acc1[4][4];
#pragma unroll
  for (int mt = 0; mt < 4; ++mt)
#pragma unroll
    for (int nt = 0; nt < 4; ++nt) acc1[mt][nt] = (f32x4){0.f, 0.f, 0.f, 0.f};

  s16x8 Aah[4], Aal[4], Abh[4], Abl[4];
  s16x8 Bah[4], Bal[4], Bbh[4], Bbl[4];
  LOAD_STAGE(Aah, Aal, Abh, Abl, 0);
  LOAD_STAGE(Bah, Bal, Bbh, Bbl, 1);
  for (int it = 0; it < 32; it += 2) {
    MFMA_STAGE(Aah, Aal, Abh, Abl);
    if (it + 2 < 32) LOAD_STAGE(Aah, Aal, Abh, Abl, it + 2);
    MFMA_STAGE(Bah, Bal, Bbh, Bbl);
    if (it + 3 < 32) LOAD_STAGE(Bah, Bal, Bbh, Bbl, it + 3);
  }

  // epilogue A: +b1, relu, split h -> LDS swizzled; MODE1: also store h.
#pragma unroll
  for (int nt = 0; nt < 4; ++nt) {
    float b1v = b1[(size_t)k * NH + wv * 64 + nt * 16 + lo];
#pragma unroll
    for (int mt = 0; mt < 4; ++mt)
#pragma unroll
      for (int i = 0; i < 4; ++i) {
        float v = acc1[mt][nt][i] + b1v;
        v = v > 0.f ? v : 0.f;
        unsigned short vh, vl;
        split2(v, vh, vl);
        int row = mt * 16 + quad * 4 + i, col = wv * 64 + nt * 16 + lo;
        int sc = col ^ ((row & 7) << 3);
        s.hs.h[row][sc] = vh;
        s.hs.l[row][sc] = vl;
        if (MODE == 1) hglob[((size_t)k * NB + r0 + row) * NH + col] = vh;
      }
  }
  __syncthreads();   // the ONE inter-phase barrier

  // ---------- phase B: recon = h@W2+b2. Wave wv owns d2-strip [wv*256, +256).
  // h A-frags dt-invariant: 2-row-tile chunk in regs, W2 streamed.
  // MODE2: store split recon (bf16) in permuted layout -> 128B/instr stores.
  float eacc[4][4];
#pragma unroll
  for (int mt = 0; mt < 4; ++mt)
#pragma unroll
    for (int i = 0; i < 4; ++i) eacc[mt][i] = 0.f;

  const int w2base = ((k * 64 + wv * 16) * 8) * 512 + lane * 8;
  const size_t rcbase = ((size_t)k * NB + (size_t)r0) * ND;   // block region

  for (int mc = 0; mc < 2; ++mc) {
    s16x8 hh[2][8], hl[2][8];
#pragma unroll
    for (int m2 = 0; m2 < 2; ++m2) {
      int row = (mc * 2 + m2) * 16 + lo;
      int rbase = row * 256;
      int sw = (row & 7) << 3;
#pragma unroll
      for (int ks = 0; ks < 8; ++ks) {
        int off = rbase + ((ks * 32 + quad * 8) ^ sw);
        hh[m2][ks] = *(const s16x8*)(&s.hs.h[0][0] + off);
        hl[m2][ks] = *(const s16x8*)(&s.hs.l[0][0] + off);
      }
    }
    for (int dt = 0; dt < 16; ++dt) {
      f32x4 acc2[2];
      acc2[0] = (f32x4){0.f, 0.f, 0.f, 0.f};
      acc2[1] = (f32x4){0.f, 0.f, 0.f, 0.f};
#pragma unroll
      for (int ks = 0; ks < 8; ++ks) {
        int wo = w2base + dt * 4096 + ks * 512;
        s16x8 bh = *(const s16x8*)&w2ph[wo];
        s16x8 bl = *(const s16x8*)&w2pl[wo];
#pragma unroll
        for (int m2 = 0; m2 < 2; ++m2) {
          acc2[m2] = __builtin_amdgcn_mfma_f32_16x16x32_bf16(hh[m2][ks], bh, acc2[m2], 0, 0, 0);
          acc2[m2] = __builtin_amdgcn_mfma_f32_16x16x32_bf16(hh[m2][ks], bl, acc2[m2], 0, 0, 0);
          acc2[m2] = __builtin_amdgcn_mfma_f32_16x16x32_bf16(hl[m2][ks], bh, acc2[m2], 0, 0, 0);
        }
      }
      const int d2 = wv * 256 + dt * 16 + lo;
      float b2v = b2[(size_t)k * ND + d2];
#pragma unroll
      for (int m2 = 0; m2 < 2; ++m2)
#pragma unroll
        for (int i = 0; i < 4; ++i) {
          int row = (mc * 2 + m2) * 16 + quad * 4 + i;
          float rec = acc2[m2][i] + b2v;
          if (MODE == 2) {
            // permuted: ((((mc*2+m2)*16+dt)*4+i)*4+wv)*64 + lane  -> 128B/instr
            size_t off = rcbase +
                (size_t)(((((mc * 2 + m2) * 16 + dt) * 4 + i) * 4 + wv) * 64 + lane);
            reconb[off] = f2bf(rec);
          }
          float xv = x[(size_t)(r0 + row) * ND + d2];
          float dd = rec - xv;
          eacc[mc * 2 + m2][i] += dd * dd;
        }
    }
  }

  __syncthreads();   // all hs reads done before errp aliases the union
#pragma unroll
  for (int mt = 0; mt < 4; ++mt)
#pragma unroll
    for (int i = 0; i < 4; ++i) {
      float v = eacc[mt][i];
      v += __shfl_xor(v, 1, 16);
      v += __shfl_xor(v, 2, 16);
      v += __shfl_xor(v, 4, 16);
      v += __shfl_xor(v, 8, 16);
      if (lo == 0) s.errp[wv][mt * 16 + quad * 4 + i] = v;
    }
  __syncthreads();
  if (tid < 64)
    err[(size_t)k * NB + r0 + tid] =
        (s.errp[0][tid] + s.errp[1][tid] + s.errp[2][tid] + s.errp[3][tid]) * (1.0f / (float)ND);
}

// ---- argmin: winner expert per row (+ bucket for fallback paths)
__global__ __launch_bounds__(256) void ae_argmin(const float* __restrict__ err,
                                                 unsigned int* __restrict__ cnt,
                                                 int* __restrict__ bucket,
                                                 int* __restrict__ assign) {
  __shared__ unsigned int lc[KE];
  __shared__ unsigned int base[KE];
  int tid = threadIdx.x;
  if (tid < KE) lc[tid] = 0;
  __syncthreads();
  int b = blockIdx.x * 256 + tid;
  float best = err[b];
  int kmin = 0;
#pragma unroll
  for (int j = 1; j < KE; ++j) {
    float e = err[(size_t)j * NB + b];
    if (e < best) { best = e; kmin = j; }   // strict < == first-min (jnp.argmin)
  }
  assign[b] = kmin;
  unsigned int lpos = atomicAdd(&lc[kmin], 1u);
  __syncthreads();
  if (tid < KE) base[tid] = atomicAdd(&cnt[tid], lc[tid]);
  __syncthreads();
  bucket[(size_t)kmin * NB + (int)(base[kmin] + lpos)] = b;
}

// ---- gather (permuted bf16 recon): out[b][d] = bf2f(reconb[map(b,d)])
// map: block (k, rtile=b>>6); row=b&63 -> mcm2=row>>4, quad=(row>>2)&3, i=row&3;
// d -> wv=d>>8, dt=(d>>4)&15, lo=d&15; lane=quad*16+lo;
// elem = ((k*NB + rtile*64)*ND) + (((mcm2*16+dt)*4+i)*4+wv)*64 + lane.
__global__ __launch_bounds__(256) void ae_gather_bf(
    const unsigned short* __restrict__ reconb,
    const int* __restrict__ assign, float* __restrict__ out) {
  const int b = blockIdx.x;
  const int kmin = assign[b];
  const int row = b & 63;
  const int mcm2 = row >> 4, quad = (row >> 2) & 3, i = row & 3;
  const size_t rcbase = ((size_t)kmin * NB + (size_t)(b & ~63)) * ND;
  const int t = threadIdx.x;
  const int d0 = t * 4;                      // 4 elems/thread, same (wv,dt)
  const int wv = d0 >> 8, dt = (d0 >> 4) & 15, lo = d0 & 15;
  const int lane = quad * 16 + lo;
  size_t off = rcbase + (size_t)((((mcm2 * 16 + dt) * 4 + i) * 4 + wv) * 64 + lane);
  u16x4 v = *(const u16x4*)&reconb[off];
  float4 o;
  o.x = bf2f(v.x); o.y = bf2f(v.y); o.z = bf2f(v.z); o.w = bf2f(v.w);
  *(float4*)&out[(size_t)b * ND + d0] = o;
}

// ---- pass 2 FAST (fallback 1): h precomputed -> phase B only.
__global__ __launch_bounds__(256) void ae_pass2_fast(
    const unsigned short* __restrict__ hglob,
    const unsigned short* __restrict__ w2ph, const float* __restrict__ b2,
    const unsigned int* __restrict__ cnt, const int* __restrict__ bucket,
    float* __restrict__ out) {
  __shared__ int rid[64];

  const int k = blockIdx.x & 7;
  const int cv = (int)cnt[k];
  const int t0 = (blockIdx.x >> 3) * 64;
  if (t0 >= cv) return;                     // uniform exit before any barrier
  const int nrows = min(64, cv - t0);

  const int tid = threadIdx.x;
  const int wv = tid >> 6;
  const int lane = tid & 63;
  const int lo = lane & 15;
  const int quad = lane >> 4;

  if (tid < 64) {
    int idx = t0 + tid;
    rid[tid] = bucket[(size_t)k * NB + (idx < cv ? idx : t0)];
  }
  __syncthreads();

  const int grow = rid[wv * 16 + lo];       // this lane's winner row
  s16x8 af[8];                              // its 8 A-frag slices (32 VGPR)
  const size_t hbase = ((size_t)k * NB + grow) * NH + quad * 8;
#pragma unroll
  for (int ks = 0; ks < 8; ++ks)
    af[ks] = *(const s16x8*)&hglob[hbase + ks * 32];

  for (int c = 0; c < 32; ++c) {
    f32x4 acc2[2];
    acc2[0] = (f32x4){0.f, 0.f, 0.f, 0.f};
    acc2[1] = (f32x4){0.f, 0.f, 0.f, 0.f};
#pragma unroll
    for (int ks = 0; ks < 8; ++ks) {
#pragma unroll
      for (int nt = 0; nt < 2; ++nt) {
        s16x8 bfr = *(const s16x8*)&w2ph[(((size_t)(k * 64 + c * 2 + nt) * 8) + ks) * 512 + lane * 8];
        acc2[nt] = __builtin_amdgcn_mfma_f32_16x16x32_bf16(af[ks], bfr, acc2[nt], 0, 0, 0);
      }
    }
#pragma unroll
    for (int nt = 0; nt < 2; ++nt) {
      float b2v = b2[(size_t)k * ND + c * 32 + nt * 16 + lo];
#pragma unroll
      for (int i = 0; i < 4; ++i) {
        int row = wv * 16 + quad * 4 + i;
        if (row < nrows)
          out[(size_t)rid[row] * ND + c * 32 + nt * 16 + lo] = acc2[nt][i] + b2v;
      }
    }
  }
}

// ---- pass 2 (fallback 2, ws tiny): recompute winner rows from x
__global__ __launch_bounds__(256) void ae_pass2(
    const float* __restrict__ x,
    const unsigned short* __restrict__ w1ph, const float* __restrict__ b1,
    const unsigned short* __restrict__ w2ph, const float* __restrict__ b2,
    const unsigned int* __restrict__ cnt, const int* __restrict__ bucket,
    float* __restrict__ out) {
  __shared__ unsigned short hs[64][NH + 8];   // 33792 B
  __shared__ unsigned short xs[64][40];       // 5120 B
  __shared__ int rid[64];

  const int k = blockIdx.x & 7;
  const int cv = (int)cnt[k];
  const int t0 = (blockIdx.x >> 3) * 64;
  if (t0 >= cv) return;                     // uniform exit before any barrier
  const int nrows = min(64, cv - t0);

  const int tid = threadIdx.x;
  const int wv = tid >> 6;
  const int lane = tid & 63;
  const int lo = lane & 15;
  const int quad = lane >> 4;
  const int srow = tid >> 2, scol = (tid & 3) * 8;

  if (tid < 64) {
    int idx = t0 + tid;
    rid[tid] = bucket[(size_t)k * NB + (idx < cv ? idx : t0)];
  }
  __syncthreads();
  const int grow = rid[srow];

  f32x4 acc1[4][4];
#pragma unroll
  for (int mt = 0; mt < 4; ++mt)
#pragma unroll
    for (int nt = 0; nt < 4; ++nt) acc1[mt][nt] = (f32x4){0.f, 0.f, 0.f, 0.f};

  for (int it = 0; it < 32; ++it) {
    float4 xa = *(const float4*)&x[(size_t)grow * ND + it * 32 + scol];
    float4 xb = *(const float4*)&x[(size_t)grow * ND + it * 32 + scol + 4];
    s16x8 bfr[4];
#pragma unroll
    for (int nt = 0; nt < 4; ++nt)
      bfr[nt] = *(const s16x8*)&w1ph[(((size_t)(k * 16 + wv * 4 + nt) * 32) + it) * 512 + lane * 8];
    __syncthreads();   // prev frag reads done
    unsigned short t[8];
    t[0] = f2bf(xa.x); t[1] = f2bf(xa.y); t[2] = f2bf(xa.z); t[3] = f2bf(xa.w);
    t[4] = f2bf(xb.x); t[5] = f2bf(xb.y); t[6] = f2bf(xb.z); t[7] = f2bf(xb.w);
    *(u16x8*)&xs[srow][scol] = *(u16x8*)t;
    __syncthreads();
    s16x8 af[4];
#pragma unroll
    for (int mt = 0; mt < 4; ++mt) af[mt] = *(const s16x8*)&xs[mt * 16 + lo][quad * 8];
#pragma unroll
    for (int mt = 0; mt < 4; ++mt)
#pragma unroll
      for (int nt = 0; nt < 4; ++nt)
        acc1[mt][nt] = __builtin_amdgcn_mfma_f32_16x16x32_bf16(af[mt], bfr[nt], acc1[mt][nt], 0, 0, 0);
  }
  __syncthreads();

#pragma unroll
  for (int nt = 0; nt < 4; ++nt) {
    float b1v = b1[(size_t)k * NH + wv * 64 + nt * 16 + lo];
#pragma unroll
    for (int mt = 0; mt < 4; ++mt)
#pragma unroll
      for (int i = 0; i < 4; ++i) {
        float v = acc1[mt][nt][i] + b1v;
        v = v > 0.f ? v : 0.f;
        hs[mt * 16 + quad * 4 + i][wv * 64 + nt * 16 + lo] = f2bf(v);
      }
  }
  __syncthreads();

  // phase B: wave wv owns rows [wv*16, +16); d2 chunks of 32; no barriers.
  for (int c = 0; c < 32; ++c) {
    f32x4 acc2[2];
    acc2[0] = (f32x4){0.f, 0.f, 0.f, 0.f};
    acc2[1] = (f32x4){0.f, 0.f, 0.f, 0.f};
#pragma unroll
    for (int ks = 0; ks < 8; ++ks) {
      s16x8 af = *(const s16x8*)&hs[wv * 16 + lo][ks * 32 + quad * 8];
#pragma unroll
      for (int nt = 0; nt < 2; ++nt) {
        s16x8 bfr = *(const s16x8*)&w2ph[(((size_t)(k * 64 + c * 2 + nt) * 8) + ks) * 512 + lane * 8];
        acc2[nt] = __builtin_amdgcn_mfma_f32_16x16x32_bf16(af, bfr, acc2[nt], 0, 0, 0);
      }
    }
#pragma unroll
    for (int nt = 0; nt < 2; ++nt) {
      float b2v = b2[(size_t)k * ND + c * 32 + nt * 16 + lo];
#pragma unroll
      for (int i = 0; i < 4; ++i) {
        int row = wv * 16 + quad * 4 + i;
        if (row < nrows)
          out[(size_t)rid[row] * ND + c * 32 + nt * 16 + lo] = acc2[nt][i] + b2v;
      }
    }
  }
}

extern "C" void kernel_launch(void* const* d_in, const int* in_sizes, int n_in,
                              void* d_out, int out_size, void* d_ws, size_t ws_size,
                              hipStream_t stream) {
  (void)in_sizes; (void)n_in; (void)out_size;
  const float* x  = (const float*)d_in[0];
  const float* W1 = (const float*)d_in[1];
  const float* b1 = (const float*)d_in[2];
  const float* W2 = (const float*)d_in[3];
  const float* b2 = (const float*)d_in[4];
  float* out = (float*)d_out;

  char* ws = (char*)d_ws;
  const size_t szW = (size_t)KE * ND * NH * sizeof(unsigned short);  // 4 MB
  const size_t szX = (size_t)NB * ND * sizeof(unsigned short);       // 16.78 MB
  unsigned short* w1ph = (unsigned short*)(ws);
  unsigned short* w1pl = (unsigned short*)(ws + szW);
  unsigned short* w2ph = (unsigned short*)(ws + 2 * szW);
  unsigned short* w2pl = (unsigned short*)(ws + 3 * szW);
  unsigned short* xph  = (unsigned short*)(ws + 4 * szW);
  unsigned short* xpl  = (unsigned short*)(ws + 4 * szW + szX);
  char* tail           = ws + 4 * szW + 2 * szX;
  float* err           = (float*)tail;
  int* bucket          = (int*)(tail + (size_t)KE * NB * sizeof(float));
  unsigned int* cnt    = (unsigned int*)(tail + (size_t)KE * NB * sizeof(float)
                                         + (size_t)KE * NB * sizeof(int));
  int* assign          = (int*)(tail + (size_t)KE * NB * sizeof(float)
                                + (size_t)KE * NB * sizeof(int) + 4096);
  // base ~48.6 MB; tiers: reconb bf16 128MB (>= ~177MB) > hglob 32MB (>= ~81MB).
  size_t base = 4 * szW + 2 * szX + (size_t)KE * NB * (sizeof(float) + sizeof(int))
                + 4096 + (size_t)NB * sizeof(int) + 4096;
  size_t rbytes = (size_t)KE * NB * ND * sizeof(unsigned short);     // 128 MB
  size_t hbytes = (size_t)KE * NB * NH * sizeof(unsigned short);     // 32 MB
  unsigned short* reconb = (ws_size >= base + rbytes)
                               ? (unsigned short*)(ws + base) : nullptr;
  unsigned short* hglob = (!reconb && ws_size >= base + hbytes)
                              ? (unsigned short*)(ws + base) : nullptr;

  pack_all<<<4608, 256, 0, stream>>>(W1, w1ph, w1pl, W2, w2ph, w2pl, x, xph, xpl, cnt);
  if (reconb)
    ae_pass1_t<2><<<1024, 256, 0, stream>>>(xph, xpl, x, w1ph, w1pl, b1,
                                            w2ph, w2pl, b2, err, nullptr, reconb);
  else if (hglob)
    ae_pass1_t<1><<<1024, 256, 0, stream>>>(xph, xpl, x, w1ph, w1pl, b1,
                                            w2ph, w2pl, b2, err, hglob, nullptr);
  else
    ae_pass1_t<0><<<1024, 256, 0, stream>>>(xph, xpl, x, w1ph, w1pl, b1,
                                            w2ph, w2pl, b2, err, nullptr, nullptr);
  ae_argmin<<<NB / 256, 256, 0, stream>>>(err, cnt, bucket, assign);
  if (reconb)
    ae_gather_bf<<<NB, 256, 0, stream>>>(reconb, assign, out);
  else if (hglob)
    ae_pass2_fast<<<1024, 256, 0, stream>>>(hglob, w2ph, b2, cnt, bucket, out);
  else
    ae_pass2<<<1024, 256, 0, stream>>>(x, w1ph, b1, w2ph, b2, cnt, bucket, out);
}